// Round 5
// baseline (7980.877 us; speedup 1.0000x reference)
//
#include <hip/hip_runtime.h>
#include <hip/hip_bf16.h>

typedef __bf16 bf16;
typedef __bf16 v8bf __attribute__((ext_vector_type(8)));

// ---------- constants ----------
#define DD 1024
#define LN_EPS 1e-5f

// output element offsets (all f32 in d_out)
#define O_Y     0
#define O_STATE 8192
#define O_IDXE  73728
#define O_RIDX  73792
#define O_WIDX  73824

// ws byte offsets (total ~17.4 MB)
#define W_KV      0ull                      // bf16 [8][1032][1024] 16908288
#define W_STATE   16908288ull               // f32  [8][8][1024]      262144
#define W_LATL    17170432ull               // f32  [8][1024]          32768
#define W_QLN     17203200ull               // f32  [8][1024]          32768
#define W_R2      17235968ull               // f32  [1024]              4096
#define W_RSC     17240064ull               // f32  [64]
#define W_SSC     17240320ull               // f32  [64]
#define W_OATT    17240576ull               // f32  [8][1024]          32768
#define W_LAT1    17273344ull
#define W_LNFFN   17306112ull
#define W_H1      17338880ull
#define W_LAT2    17371648ull

__device__ __forceinline__ float wred_sum(float v) {
#pragma unroll
  for (int o = 32; o; o >>= 1) v += __shfl_down(v, o, 64);
  return v;
}

__device__ __forceinline__ void top4_of8(const float* sc, int* ridx) {
  unsigned used = 0;
#pragma unroll
  for (int k = 0; k < 4; k++) {
    float best = -3.4e38f; int bi = 0;
    for (int s = 0; s < 8; s++)
      if (!((used >> s) & 1) && sc[s] > best) { best = sc[s]; bi = s; }
    used |= 1u << bi; ridx[k] = bi;
  }
}

// ---------- r2 = row norms of A_skew ----------
__global__ __launch_bounds__(256) void k_r2(const float* __restrict__ A, float* __restrict__ r2) {
  int row = blockIdx.x, t = threadIdx.x;
  const float* p = A + (size_t)row * DD;
  float s = 0.f;
  for (int j = t; j < DD; j += 256) { float x = p[j]; s += x * x; }
  s = wred_sum(s);
  __shared__ float sh[4];
  if ((t & 63) == 0) sh[t >> 6] = s;
  __syncthreads();
  if (t == 0) r2[row] = sh[0] + sh[1] + sh[2] + sh[3];
}

// ---------- read_scores + slot_scores ----------
__global__ __launch_bounds__(256) void k_scores(const float* __restrict__ state,
    const float* __restrict__ W_rg, const float* __restrict__ g_sl, const float* __restrict__ b_sl,
    const float* __restrict__ W_sl, float* __restrict__ rsc, float* __restrict__ ssc) {
  int row = blockIdx.x, t = threadIdx.x, l = t & 63, w = t >> 6;
  const float* p = state + (size_t)row * DD;
  float x[4]; float sum = 0.f, sq = 0.f, rs = 0.f;
#pragma unroll
  for (int i = 0; i < 4; i++) {
    int j = t + i * 256;
    x[i] = p[j];
    sum += x[i]; sq += x[i] * x[i];
    rs += x[i] * W_rg[j];
  }
  __shared__ float sh[3][4];
  sum = wred_sum(sum); sq = wred_sum(sq); rs = wred_sum(rs);
  if (l == 0) { sh[0][w] = sum; sh[1][w] = sq; sh[2][w] = rs; }
  __syncthreads();
  float m = (sh[0][0] + sh[0][1] + sh[0][2] + sh[0][3]) * (1.0f / 1024.0f);
  float var = (sh[1][0] + sh[1][1] + sh[1][2] + sh[1][3]) * (1.0f / 1024.0f) - m * m;
  float rsTot = sh[2][0] + sh[2][1] + sh[2][2] + sh[2][3];
  float inv = 1.0f / sqrtf(var + LN_EPS);
  __syncthreads();
  float ss = 0.f;
#pragma unroll
  for (int i = 0; i < 4; i++) {
    int j = t + i * 256;
    float ln = (x[i] - m) * inv * g_sl[j] + b_sl[j];
    ss += ln * W_sl[j];
  }
  ss = wred_sum(ss);
  if (l == 0) sh[0][w] = ss;
  __syncthreads();
  if (t == 0) { rsc[row] = rsTot; ssc[row] = sh[0][0] + sh[0][1] + sh[0][2] + sh[0][3]; }
}

// ---------- gate: LN_moe + gate logits + top2 -> idx_experts, read_idx (f32 out) ----------
__global__ __launch_bounds__(256) void k_gate(const float* __restrict__ state,
    const float* __restrict__ rsc, const float* __restrict__ g_moe, const float* __restrict__ b_moe,
    const float* __restrict__ Wg, float* __restrict__ out) {
  int b = blockIdx.x >> 2, k = blockIdx.x & 3;
  int t = threadIdx.x, l = t & 63, w = t >> 6;
  __shared__ float rs[8];
  __shared__ float red[2][4];
  __shared__ float gl[8];
  if (t < 8) rs[t] = rsc[b * 8 + t];
  __syncthreads();
  int ridx[4]; top4_of8(rs, ridx);
  int s = ridx[k];
  const float* p = state + (size_t)(b * 8 + s) * DD;
  float x[4]; float sum = 0.f, sq = 0.f;
#pragma unroll
  for (int i = 0; i < 4; i++) {
    int j = t + i * 256;
    x[i] = p[j]; sum += x[i]; sq += x[i] * x[i];
  }
  sum = wred_sum(sum); sq = wred_sum(sq);
  if (l == 0) { red[0][w] = sum; red[1][w] = sq; }
  __syncthreads();
  float m = (red[0][0] + red[0][1] + red[0][2] + red[0][3]) * (1.0f / 1024.0f);
  float var = (red[1][0] + red[1][1] + red[1][2] + red[1][3]) * (1.0f / 1024.0f) - m * m;
  float inv = 1.0f / sqrtf(var + LN_EPS);
  float lnv[4];
#pragma unroll
  for (int i = 0; i < 4; i++) {
    int j = t + i * 256;
    lnv[i] = (x[i] - m) * inv * g_moe[j] + b_moe[j];
  }
  __syncthreads();
  for (int e = 0; e < 8; e++) {
    float acc = 0.f;
#pragma unroll
    for (int i = 0; i < 4; i++) acc += lnv[i] * Wg[(size_t)e * DD + t + i * 256];
    acc = wred_sum(acc);
    if (l == 0) red[0][w] = acc;
    __syncthreads();
    if (t == 0) gl[e] = red[0][0] + red[0][1] + red[0][2] + red[0][3];
    __syncthreads();
  }
  if (t == 0) {
    int e0 = 0, e1 = 0; float b0 = -3.4e38f, b1 = -3.4e38f;
    for (int e = 0; e < 8; e++) {
      float v = gl[e];
      if (v > b0) { b1 = b0; e1 = e0; b0 = v; e0 = e; }
      else if (v > b1) { b1 = v; e1 = e; }
    }
    out[O_IDXE + (b * 4 + k) * 2 + 0] = (float)e0;
    out[O_IDXE + (b * 4 + k) * 2 + 1] = (float)e1;
    if (k == 0)
      for (int kk = 0; kk < 4; kk++) out[O_RIDX + b * 4 + kk] = (float)ridx[kk];
  }
}

// ---------- state update (f32 out) ----------
__global__ __launch_bounds__(256) void k_state(const float* __restrict__ state_in,
    const float* __restrict__ rsc, const float* __restrict__ ssc, const float* __restrict__ r2,
    float* __restrict__ state_ws, float* __restrict__ out) {
  int b = blockIdx.x, t = threadIdx.x;
  __shared__ float rs[8];
  if (t < 8) rs[t] = rsc[b * 8 + t];
  __syncthreads();
  int ridx[4]; top4_of8(rs, ridx);
  float lr[4];
#pragma unroll
  for (int k = 0; k < 4; k++) lr[k] = ssc[b * 8 + ridx[k]];
  int w0 = 0, w1 = 0; float b0 = -3.4e38f, b1 = -3.4e38f;
#pragma unroll
  for (int k = 0; k < 4; k++) {
    float v = lr[k];
    if (v > b0) { b1 = b0; w1 = w0; b0 = v; w0 = k; }
    else if (v > b1) { b1 = v; w1 = k; }
  }
  int wid0 = ridx[w0], wid1 = ridx[w1];
  float mx = fmaxf(lr[0], lr[1]);
  float e0 = expf(lr[0] - mx), e1 = expf(lr[1] - mx);
  float den = e0 + e1;
  float ws0 = e0 / den, ws1 = e1 / den;
  float resid = 1.0f - (ws0 + ws1);
#pragma unroll
  for (int i = 0; i < 4; i++) {
    int j = t + i * 256;
    float q = 1.0f - 0.03125f * r2[j];  // diag Cayley, c=0.125, O(c^4) dropped
    float lca = 0.f;
#pragma unroll
    for (int k = 0; k < 4; k++)
      lca += tanhf(state_in[(size_t)(b * 8 + ridx[k]) * DD + j] * q);
    float tj = tanhf(lca * 0.25f);
#pragma unroll
    for (int s = 0; s < 8; s++) {
      float a = (s == wid0) ? ws0 : ((s == wid1) ? ws1 : 0.0f);
      float v = a * tj + resid * state_in[(size_t)(b * 8 + s) * DD + j];
      state_ws[(size_t)(b * 8 + s) * DD + j] = v;
      out[O_STATE + (size_t)(b * 8 + s) * DD + j] = v;
    }
  }
  if (t == 0) {
    out[O_WIDX + b * 2 + 0] = (float)wid0;
    out[O_WIDX + b * 2 + 1] = (float)wid1;
  }
}

// ---------- f32 VALU GEMM: C[m,n] = sum_k A[m,k]*B[n,k] + bias + PE ----------
// 128x128 tile, BK=8, 256 threads, 8x8 acc/thread. Writes bf16 kvbuf; row 1023 also f32 lat_last.
__global__ __launch_bounds__(256) void k_gemm_f32(const float* __restrict__ A,
    const float* __restrict__ Bm, const float* __restrict__ bias, bf16* __restrict__ kvbuf,
    float* __restrict__ lat_last) {
  __shared__ float As[8][129];
  __shared__ float Bs[8][129];
  const int t = threadIdx.x;
  const int mbase = blockIdx.y * 128, nbase = blockIdx.x * 128;
  const int tm = (t >> 4) * 8, tn = (t & 15) * 8;
  float acc[8][8] = {};
  for (int k0 = 0; k0 < 1024; k0 += 8) {
#pragma unroll
    for (int u2 = 0; u2 < 4; u2++) {
      int li = t * 4 + u2;        // 0..1023 over [128 rows][8 k]
      int r = li >> 3, c = li & 7;
      As[c][r] = A[(size_t)(mbase + r) * 1024 + k0 + c];
      Bs[c][r] = Bm[(size_t)(nbase + r) * 1024 + k0 + c];
    }
    __syncthreads();
#pragma unroll
    for (int kk = 0; kk < 8; kk++) {
      float a[8], b[8];
#pragma unroll
      for (int i = 0; i < 8; i++) a[i] = As[kk][tm + i];
#pragma unroll
      for (int j = 0; j < 8; j++) b[j] = Bs[kk][tn + j];
#pragma unroll
      for (int i = 0; i < 8; i++)
#pragma unroll
        for (int j = 0; j < 8; j++) acc[i][j] += a[i] * b[j];
    }
    __syncthreads();
  }
#pragma unroll
  for (int i = 0; i < 8; i++)
#pragma unroll
    for (int j = 0; j < 8; j++) {
      int row = mbase + tm + i;
      int col = nbase + tn + j;
      int tok = row & 1023, bb = row >> 10;
      int i2 = col & 511;                              // PE: base 8, half=512
      float f = exp2f((float)i2 * (3.0f / 512.0f));    // 8^(i2/512)
      float a = (float)tok / f;
      float pe = (col < 512) ? sinf(a) : cosf(a);
      float v = acc[i][j] + bias[col] + pe;
      kvbuf[((size_t)bb * 1032 + tok) * 1024 + col] = (bf16)v;
      if (tok == 1023) lat_last[(size_t)bb * 1024 + col] = v;
    }
}

// ---------- LN (in-place on kv token rows; state rows from f32; q row from f32 lat_last) ----------
__global__ __launch_bounds__(256) void k_ln(bf16* __restrict__ kvbuf,
    const float* __restrict__ state_ws, const float* __restrict__ gkv, const float* __restrict__ bkv,
    const float* __restrict__ gq, const float* __restrict__ bq,
    float* __restrict__ qln, const float* __restrict__ lat_last) {
  int r = blockIdx.x, t = threadIdx.x, l = t & 63, w = t >> 6;
  int b = r / 1032, p = r % 1032;
  bf16* row = kvbuf + ((size_t)b * 1032 + p) * DD;
  float x[4]; float sum = 0.f, sq = 0.f;
  if (p == 1023) {
    const float* src = lat_last + (size_t)b * DD;   // full-precision latent row 1023
#pragma unroll
    for (int i = 0; i < 4; i++) {
      int j = t + i * 256;
      x[i] = src[j]; sum += x[i]; sq += x[i] * x[i];
    }
  } else if (p < 1024) {
#pragma unroll
    for (int i = 0; i < 4; i++) {
      int j = t + i * 256;
      x[i] = (float)row[j]; sum += x[i]; sq += x[i] * x[i];
    }
  } else {
    const float* src = state_ws + ((size_t)b * 8 + (p - 1024)) * DD;
#pragma unroll
    for (int i = 0; i < 4; i++) {
      int j = t + i * 256;
      x[i] = src[j]; sum += x[i]; sq += x[i] * x[i];
    }
  }
  __shared__ float sh[2][4];
  sum = wred_sum(sum); sq = wred_sum(sq);
  if (l == 0) { sh[0][w] = sum; sh[1][w] = sq; }
  __syncthreads();
  float m = (sh[0][0] + sh[0][1] + sh[0][2] + sh[0][3]) * (1.0f / 1024.0f);
  float var = (sh[1][0] + sh[1][1] + sh[1][2] + sh[1][3]) * (1.0f / 1024.0f) - m * m;
  float inv = 1.0f / sqrtf(var + LN_EPS);
  if (p == 1023) {
#pragma unroll
    for (int i = 0; i < 4; i++) {
      int j = t + i * 256;
      qln[(size_t)b * DD + j] = (x[i] - m) * inv * gq[j] + bq[j];
    }
  }
#pragma unroll
  for (int i = 0; i < 4; i++) {
    int j = t + i * 256;
    row[j] = (bf16)((x[i] - m) * inv * gkv[j] + bkv[j]);
  }
}

// ---------- LN of one f32 row per block (ffn pre-LN) ----------
__global__ __launch_bounds__(256) void k_ln_row(const float* __restrict__ src,
    const float* __restrict__ g, const float* __restrict__ bb, float* __restrict__ dst) {
  int b = blockIdx.x, t = threadIdx.x, l = t & 63, w = t >> 6;
  const float* p = src + (size_t)b * DD;
  float x[4]; float sum = 0.f, sq = 0.f;
#pragma unroll
  for (int i = 0; i < 4; i++) {
    int j = t + i * 256;
    x[i] = p[j]; sum += x[i]; sq += x[i] * x[i];
  }
  __shared__ float sh[2][4];
  sum = wred_sum(sum); sq = wred_sum(sq);
  if (l == 0) { sh[0][w] = sum; sh[1][w] = sq; }
  __syncthreads();
  float m = (sh[0][0] + sh[0][1] + sh[0][2] + sh[0][3]) * (1.0f / 1024.0f);
  float var = (sh[1][0] + sh[1][1] + sh[1][2] + sh[1][3]) * (1.0f / 1024.0f) - m * m;
  float inv = 1.0f / sqrtf(var + LN_EPS);
#pragma unroll
  for (int i = 0; i < 4; i++) {
    int j = t + i * 256;
    dst[(size_t)b * DD + j] = (x[i] - m) * inv * g[j] + bb[j];
  }
}

// ---------- attention per (b,h): u = Wk^T qp, logits = u.kv, o = Wv.(sum w kv) ----------
__global__ __launch_bounds__(256) void k_attn(const float* __restrict__ qln,
    const bf16* __restrict__ kvbuf, const float* __restrict__ Wi, const float* __restrict__ bi,
    float* __restrict__ o) {
  int b = blockIdx.x >> 3, h = blockIdx.x & 7;
  int t = threadIdx.x, l = t & 63, w = t >> 6;
  __shared__ float qp[128];
  __shared__ float u[1024];
  __shared__ float lg[1032];
  __shared__ float red[4];
  const float* qr = qln + (size_t)b * DD;
  // phase 1: q projection (head slice)
  for (int d = w; d < 128; d += 4) {
    int n = h * 128 + d;
    const float* wr = Wi + (size_t)n * DD;
    float acc = 0.f;
    for (int k = l; k < 1024; k += 64) acc += qr[k] * wr[k];
    acc = wred_sum(acc);
    if (l == 0) qp[d] = acc + bi[n];
  }
  __syncthreads();
  // phase 2: u[k] = sum_d qp[d] * Wk[h*128+d][k]; c0 = qp . bk_slice
  float uj[4] = {0.f, 0.f, 0.f, 0.f};
  const float* Wk = Wi + (size_t)1024 * DD;
  for (int d = 0; d < 128; d++) {
    const float* wr = Wk + (size_t)(h * 128 + d) * DD;
    float q = qp[d];
#pragma unroll
    for (int j = 0; j < 4; j++) uj[j] += q * wr[t + j * 256];
  }
  float c0 = 0.f;
  for (int d = 0; d < 128; d++) c0 += qp[d] * bi[1024 + h * 128 + d];
#pragma unroll
  for (int j = 0; j < 4; j++) u[t + j * 256] = uj[j];
  __syncthreads();
  // phase 3: logits over 1032 kv rows
  const float scale = 0.08838834764831845f;  // 1/sqrt(128)
  const bf16* kvb = kvbuf + (size_t)b * 1032 * DD;
  for (int p = t; p < 1032; p += 256) {
    const bf16* kr = kvb + (size_t)p * DD;
    float acc = 0.f;
    for (int k = 0; k < 1024; k += 8) {
      v8bf kv8 = *(const v8bf*)(kr + k);
#pragma unroll
      for (int q8 = 0; q8 < 8; q8++) acc += u[k + q8] * (float)kv8[q8];
    }
    lg[p] = (acc + c0) * scale;
  }
  __syncthreads();
  // phase 4: softmax
  float mx = -3.4e38f;
  for (int p = t; p < 1032; p += 256) mx = fmaxf(mx, lg[p]);
#pragma unroll
  for (int o2 = 32; o2; o2 >>= 1) mx = fmaxf(mx, __shfl_down(mx, o2, 64));
  if (l == 0) red[w] = mx;
  __syncthreads();
  mx = fmaxf(fmaxf(red[0], red[1]), fmaxf(red[2], red[3]));
  __syncthreads();
  float sume = 0.f;
  for (int p = t; p < 1032; p += 256) { float e = expf(lg[p] - mx); lg[p] = e; sume += e; }
  sume = wred_sum(sume);
  if (l == 0) red[w] = sume;
  __syncthreads();
  float invden = 1.0f / (red[0] + red[1] + red[2] + red[3]);
  // phase 5: s[k] = sum_p w_p * kv[p][k]
  float sj[4] = {0.f, 0.f, 0.f, 0.f};
  for (int p = 0; p < 1032; p++) {
    float wp = lg[p];
    const bf16* kr = kvb + (size_t)p * DD;
#pragma unroll
    for (int j = 0; j < 4; j++) sj[j] += wp * (float)kr[t + j * 256];
  }
  __syncthreads();
#pragma unroll
  for (int j = 0; j < 4; j++) u[t + j * 256] = sj[j] * invden;
  __syncthreads();
  // phase 6: o = Wv . s + bv
  const float* Wv = Wi + (size_t)2048 * DD;
  for (int d = w; d < 128; d += 4) {
    int n = h * 128 + d;
    const float* wr = Wv + (size_t)n * DD;
    float acc = 0.f;
    for (int k = l; k < 1024; k += 64) acc += u[k] * wr[k];
    acc = wred_sum(acc);
    if (l == 0) o[(size_t)b * DD + n] = acc + bi[2048 + n];
  }
}

// ---------- tail GEMVs: one wave per output element ----------
// MODE 0: out_proj + residual(lat_last)  1: fc1+gelu  2: fc2+residual  3: W_out -> f32 y
template <int MODE>
__global__ __launch_bounds__(256) void k_gemv(const float* __restrict__ xin,
    const float* __restrict__ W, const float* __restrict__ bias,
    const float* __restrict__ res, float* __restrict__ outf) {
  int idx = blockIdx.x * 4 + (threadIdx.x >> 6);
  int l = threadIdx.x & 63;
  int b = idx >> 10, n = idx & 1023;
  const float* xr = xin + (size_t)b * DD;
  const float* wr = W + (size_t)n * DD;
  float acc = 0.f;
#pragma unroll
  for (int k0 = 0; k0 < 1024; k0 += 64) acc += xr[k0 + l] * wr[k0 + l];
  acc = wred_sum(acc);
  if (l == 0) {
    float v = acc + bias[n];
    if (MODE == 0) outf[idx] = res[idx] + v;
    if (MODE == 1) outf[idx] = 0.5f * v * (1.0f + erff(v * 0.70710678118654752f));
    if (MODE == 2) outf[idx] = res[idx] + v;
    if (MODE == 3) outf[O_Y + idx] = v;
  }
}

extern "C" void kernel_launch(void* const* d_in, const int* in_sizes, int n_in,
                              void* d_out, int out_size, void* d_ws, size_t ws_size,
                              hipStream_t stream) {
  const float* x        = (const float*)d_in[0];
  const float* state_in = (const float*)d_in[1];
  const float* W_rg     = (const float*)d_in[2];
  const float* ln_moe_g = (const float*)d_in[3];
  const float* ln_moe_b = (const float*)d_in[4];
  const float* W_gate   = (const float*)d_in[5];
  const float* A_skew   = (const float*)d_in[6];
  const float* ln_sl_g  = (const float*)d_in[7];
  const float* ln_sl_b  = (const float*)d_in[8];
  const float* W_slot   = (const float*)d_in[9];
  const float* W_oe     = (const float*)d_in[10];
  const float* b_oe     = (const float*)d_in[11];
  const float* ln_q_g   = (const float*)d_in[12];
  const float* ln_q_b   = (const float*)d_in[13];
  const float* ln_kv_g  = (const float*)d_in[14];
  const float* ln_kv_b  = (const float*)d_in[15];
  const float* in_w     = (const float*)d_in[16];
  const float* in_b     = (const float*)d_in[17];
  const float* out_w    = (const float*)d_in[18];
  const float* out_b    = (const float*)d_in[19];
  const float* ln_f_g   = (const float*)d_in[20];
  const float* ln_f_b   = (const float*)d_in[21];
  const float* W_fc1    = (const float*)d_in[22];
  const float* b_fc1    = (const float*)d_in[23];
  const float* W_fc2    = (const float*)d_in[24];
  const float* b_fc2    = (const float*)d_in[25];
  const float* W_out    = (const float*)d_in[26];
  const float* b_out    = (const float*)d_in[27];

  char* ws = (char*)d_ws;
  bf16*  kvbuf    = (bf16*)(ws + W_KV);
  float* state_ws = (float*)(ws + W_STATE);
  float* lat_last = (float*)(ws + W_LATL);
  float* qln      = (float*)(ws + W_QLN);
  float* r2       = (float*)(ws + W_R2);
  float* rsc      = (float*)(ws + W_RSC);
  float* ssc      = (float*)(ws + W_SSC);
  float* o_attn   = (float*)(ws + W_OATT);
  float* lat1     = (float*)(ws + W_LAT1);
  float* lnffn    = (float*)(ws + W_LNFFN);
  float* h1       = (float*)(ws + W_H1);
  float* lat2     = (float*)(ws + W_LAT2);
  float* out = (float*)d_out;

  k_r2<<<1024, 256, 0, stream>>>(A_skew, r2);
  k_scores<<<64, 256, 0, stream>>>(state_in, W_rg, ln_sl_g, ln_sl_b, W_slot, rsc, ssc);
  k_gate<<<32, 256, 0, stream>>>(state_in, rsc, ln_moe_g, ln_moe_b, W_gate, out);
  k_state<<<8, 256, 0, stream>>>(state_in, rsc, ssc, r2, state_ws, out);
  k_gemm_f32<<<dim3(8, 64), 256, 0, stream>>>(x, W_oe, b_oe, kvbuf, lat_last);
  k_ln<<<8256, 256, 0, stream>>>(kvbuf, state_ws, ln_kv_g, ln_kv_b, ln_q_g, ln_q_b, qln, lat_last);
  k_attn<<<64, 256, 0, stream>>>(qln, kvbuf, in_w, in_b, o_attn);
  k_gemv<0><<<2048, 256, 0, stream>>>(o_attn, out_w, out_b, lat_last, lat1);
  k_ln_row<<<8, 256, 0, stream>>>(lat1, ln_f_g, ln_f_b, lnffn);
  k_gemv<1><<<2048, 256, 0, stream>>>(lnffn, W_fc1, b_fc1, nullptr, h1);
  k_gemv<2><<<2048, 256, 0, stream>>>(h1, W_fc2, b_fc2, lat1, lat2);
  k_gemv<3><<<2048, 256, 0, stream>>>(lat2, W_out, b_out, nullptr, out);
}

// Round 7
// 1128.762 us; speedup vs baseline: 7.0705x; 7.0705x over previous
//
#include <hip/hip_runtime.h>
#include <hip/hip_bf16.h>

typedef __bf16 bf16;
typedef __bf16 v8bf __attribute__((ext_vector_type(8)));
typedef float v4f __attribute__((ext_vector_type(4)));

// ---------- constants ----------
#define DD 1024
#define LN_EPS 1e-5f

// output element offsets (all f32 in d_out)
#define O_Y     0
#define O_STATE 8192
#define O_IDXE  73728
#define O_RIDX  73792
#define O_WIDX  73824

// ws byte offsets (total 17404416 B — exact round-5 layout, proven in-bounds)
#define W_KV      0ull                      // bf16 [8][1032][1024] 16908288
#define W_STATE   16908288ull               // f32  [8][8][1024]      262144
#define W_LATL    17170432ull               // f32  [8][1024]          32768
#define W_QLN     17203200ull               // f32  [8][1024]          32768
#define W_R2      17235968ull               // f32  [1024]              4096
#define W_RSC     17240064ull               // f32  [64]
#define W_SSC     17240320ull               // f32  [64]
#define W_OATT    17240576ull               // f32  [8][1024]          32768
#define W_LAT1    17273344ull
#define W_LNFFN   17306112ull
#define W_H1      17338880ull
#define W_LAT2    17371648ull

__device__ __forceinline__ float wred_sum(float v) {
#pragma unroll
  for (int o = 32; o; o >>= 1) v += __shfl_down(v, o, 64);
  return v;
}

__device__ __forceinline__ void top4_of8(const float* sc, int* ridx) {
  unsigned used = 0;
#pragma unroll
  for (int k = 0; k < 4; k++) {
    float best = -3.4e38f; int bi = 0;
    for (int s = 0; s < 8; s++)
      if (!((used >> s) & 1) && sc[s] > best) { best = sc[s]; bi = s; }
    used |= 1u << bi; ridx[k] = bi;
  }
}

// ---------- r2 = row norms of A_skew ----------
__global__ __launch_bounds__(256) void k_r2(const float* __restrict__ A, float* __restrict__ r2) {
  int row = blockIdx.x, t = threadIdx.x;
  const float* p = A + (size_t)row * DD;
  float s = 0.f;
  for (int j = t; j < DD; j += 256) { float x = p[j]; s += x * x; }
  s = wred_sum(s);
  __shared__ float sh[4];
  if ((t & 63) == 0) sh[t >> 6] = s;
  __syncthreads();
  if (t == 0) r2[row] = sh[0] + sh[1] + sh[2] + sh[3];
}

// ---------- read_scores + slot_scores ----------
__global__ __launch_bounds__(256) void k_scores(const float* __restrict__ state,
    const float* __restrict__ W_rg, const float* __restrict__ g_sl, const float* __restrict__ b_sl,
    const float* __restrict__ W_sl, float* __restrict__ rsc, float* __restrict__ ssc) {
  int row = blockIdx.x, t = threadIdx.x, l = t & 63, w = t >> 6;
  const float* p = state + (size_t)row * DD;
  float x[4]; float sum = 0.f, sq = 0.f, rs = 0.f;
#pragma unroll
  for (int i = 0; i < 4; i++) {
    int j = t + i * 256;
    x[i] = p[j];
    sum += x[i]; sq += x[i] * x[i];
    rs += x[i] * W_rg[j];
  }
  __shared__ float sh[3][4];
  sum = wred_sum(sum); sq = wred_sum(sq); rs = wred_sum(rs);
  if (l == 0) { sh[0][w] = sum; sh[1][w] = sq; sh[2][w] = rs; }
  __syncthreads();
  float m = (sh[0][0] + sh[0][1] + sh[0][2] + sh[0][3]) * (1.0f / 1024.0f);
  float var = (sh[1][0] + sh[1][1] + sh[1][2] + sh[1][3]) * (1.0f / 1024.0f) - m * m;
  float rsTot = sh[2][0] + sh[2][1] + sh[2][2] + sh[2][3];
  float inv = 1.0f / sqrtf(var + LN_EPS);
  __syncthreads();
  float ss = 0.f;
#pragma unroll
  for (int i = 0; i < 4; i++) {
    int j = t + i * 256;
    float ln = (x[i] - m) * inv * g_sl[j] + b_sl[j];
    ss += ln * W_sl[j];
  }
  ss = wred_sum(ss);
  if (l == 0) sh[0][w] = ss;
  __syncthreads();
  if (t == 0) { rsc[row] = rsTot; ssc[row] = sh[0][0] + sh[0][1] + sh[0][2] + sh[0][3]; }
}

// ---------- gate: LN_moe + gate logits + top2 -> idx_experts, read_idx (f32 out) ----------
__global__ __launch_bounds__(256) void k_gate(const float* __restrict__ state,
    const float* __restrict__ rsc, const float* __restrict__ g_moe, const float* __restrict__ b_moe,
    const float* __restrict__ Wg, float* __restrict__ out) {
  int b = blockIdx.x >> 2, k = blockIdx.x & 3;
  int t = threadIdx.x, l = t & 63, w = t >> 6;
  __shared__ float rs[8];
  __shared__ float red[2][4];
  __shared__ float gl[8];
  if (t < 8) rs[t] = rsc[b * 8 + t];
  __syncthreads();
  int ridx[4]; top4_of8(rs, ridx);
  int s = ridx[k];
  const float* p = state + (size_t)(b * 8 + s) * DD;
  float x[4]; float sum = 0.f, sq = 0.f;
#pragma unroll
  for (int i = 0; i < 4; i++) {
    int j = t + i * 256;
    x[i] = p[j]; sum += x[i]; sq += x[i] * x[i];
  }
  sum = wred_sum(sum); sq = wred_sum(sq);
  if (l == 0) { red[0][w] = sum; red[1][w] = sq; }
  __syncthreads();
  float m = (red[0][0] + red[0][1] + red[0][2] + red[0][3]) * (1.0f / 1024.0f);
  float var = (red[1][0] + red[1][1] + red[1][2] + red[1][3]) * (1.0f / 1024.0f) - m * m;
  float inv = 1.0f / sqrtf(var + LN_EPS);
  float lnv[4];
#pragma unroll
  for (int i = 0; i < 4; i++) {
    int j = t + i * 256;
    lnv[i] = (x[i] - m) * inv * g_moe[j] + b_moe[j];
  }
  __syncthreads();
  for (int e = 0; e < 8; e++) {
    float acc = 0.f;
#pragma unroll
    for (int i = 0; i < 4; i++) acc += lnv[i] * Wg[(size_t)e * DD + t + i * 256];
    acc = wred_sum(acc);
    if (l == 0) red[0][w] = acc;
    __syncthreads();
    if (t == 0) gl[e] = red[0][0] + red[0][1] + red[0][2] + red[0][3];
    __syncthreads();
  }
  if (t == 0) {
    int e0 = 0, e1 = 0; float b0 = -3.4e38f, b1 = -3.4e38f;
    for (int e = 0; e < 8; e++) {
      float v = gl[e];
      if (v > b0) { b1 = b0; e1 = e0; b0 = v; e0 = e; }
      else if (v > b1) { b1 = v; e1 = e; }
    }
    out[O_IDXE + (b * 4 + k) * 2 + 0] = (float)e0;
    out[O_IDXE + (b * 4 + k) * 2 + 1] = (float)e1;
    if (k == 0)
      for (int kk = 0; kk < 4; kk++) out[O_RIDX + b * 4 + kk] = (float)ridx[kk];
  }
}

// ---------- state update (f32 out) ----------
__global__ __launch_bounds__(256) void k_state(const float* __restrict__ state_in,
    const float* __restrict__ rsc, const float* __restrict__ ssc, const float* __restrict__ r2,
    float* __restrict__ state_ws, float* __restrict__ out) {
  int b = blockIdx.x, t = threadIdx.x;
  __shared__ float rs[8];
  if (t < 8) rs[t] = rsc[b * 8 + t];
  __syncthreads();
  int ridx[4]; top4_of8(rs, ridx);
  float lr[4];
#pragma unroll
  for (int k = 0; k < 4; k++) lr[k] = ssc[b * 8 + ridx[k]];
  int w0 = 0, w1 = 0; float b0 = -3.4e38f, b1 = -3.4e38f;
#pragma unroll
  for (int k = 0; k < 4; k++) {
    float v = lr[k];
    if (v > b0) { b1 = b0; w1 = w0; b0 = v; w0 = k; }
    else if (v > b1) { b1 = v; w1 = k; }
  }
  int wid0 = ridx[w0], wid1 = ridx[w1];
  float mx = fmaxf(lr[0], lr[1]);
  float e0 = expf(lr[0] - mx), e1 = expf(lr[1] - mx);
  float den = e0 + e1;
  float ws0 = e0 / den, ws1 = e1 / den;
  float resid = 1.0f - (ws0 + ws1);
#pragma unroll
  for (int i = 0; i < 4; i++) {
    int j = t + i * 256;
    float q = 1.0f - 0.03125f * r2[j];  // diag Cayley, c=0.125, O(c^4) dropped
    float lca = 0.f;
#pragma unroll
    for (int k = 0; k < 4; k++)
      lca += tanhf(state_in[(size_t)(b * 8 + ridx[k]) * DD + j] * q);
    float tj = tanhf(lca * 0.25f);
#pragma unroll
    for (int s = 0; s < 8; s++) {
      float a = (s == wid0) ? ws0 : ((s == wid1) ? ws1 : 0.0f);
      float v = a * tj + resid * state_in[(size_t)(b * 8 + s) * DD + j];
      state_ws[(size_t)(b * 8 + s) * DD + j] = v;
      out[O_STATE + (size_t)(b * 8 + s) * DD + j] = v;
    }
  }
  if (t == 0) {
    out[O_WIDX + b * 2 + 0] = (float)wid0;
    out[O_WIDX + b * 2 + 1] = (float)wid1;
  }
}

// ---------- MFMA BT GEMM, f32 inputs with in-register cvt + ds_write staging ----------
// C[m,n] = sum_k A[m,k]*B[n,k] + bias + PE. 128x128 tile, BK=32.
// Writes bf16 kvbuf; row 1023 also f32 lat_last.
__global__ __launch_bounds__(256, 2) void k_gemm(const float* __restrict__ A,
    const float* __restrict__ Bm, const float* __restrict__ bias, bf16* __restrict__ kvbuf,
    float* __restrict__ lat_last) {
  __shared__ bf16 As[128 * 32];
  __shared__ bf16 Bs[128 * 32];
  const int t = threadIdx.x, l = t & 63, w = t >> 6;
  const int mbase = blockIdx.y * 128, nbase = blockIdx.x * 128;
  const int wm = (w >> 1) * 64, wn = (w & 1) * 64;
  const int lm = l & 15, lk = (l >> 4) * 8;
  v4f acc[4][4];
#pragma unroll
  for (int i = 0; i < 4; i++)
#pragma unroll
    for (int j = 0; j < 4; j++) acc[i][j] = (v4f){0.f, 0.f, 0.f, 0.f};

  const int srow = t >> 1;          // 0..127: tile row this thread stages
  const int skc = (t & 1) * 16;     // 0 or 16: k-offset within BK=32
  for (int k0 = 0; k0 < 1024; k0 += 32) {
    // issue f32 global loads early (overlap with previous iter's MFMA tail)
    const float* ap = A + (size_t)(mbase + srow) * 1024 + k0 + skc;
    const float* bp = Bm + (size_t)(nbase + srow) * 1024 + k0 + skc;
    float af32[16], bf32[16];
#pragma unroll
    for (int q = 0; q < 4; q++) {
      v4f va = *(const v4f*)(ap + q * 4);
      v4f vb = *(const v4f*)(bp + q * 4);
#pragma unroll
      for (int r = 0; r < 4; r++) { af32[q * 4 + r] = va[r]; bf32[q * 4 + r] = vb[r]; }
    }
    __syncthreads();   // previous iter's LDS reads complete before overwrite
    v8bf pa, pb;
#pragma unroll
    for (int q = 0; q < 8; q++) { pa[q] = (bf16)af32[q]; pb[q] = (bf16)bf32[q]; }
    *(v8bf*)(As + srow * 32 + skc) = pa;
    *(v8bf*)(Bs + srow * 32 + skc) = pb;
#pragma unroll
    for (int q = 0; q < 8; q++) { pa[q] = (bf16)af32[8 + q]; pb[q] = (bf16)bf32[8 + q]; }
    *(v8bf*)(As + srow * 32 + skc + 8) = pa;
    *(v8bf*)(Bs + srow * 32 + skc + 8) = pb;
    __syncthreads();
    v8bf af[4], bfr[4];
#pragma unroll
    for (int i = 0; i < 4; i++) af[i] = *(const v8bf*)(As + (wm + i * 16 + lm) * 32 + lk);
#pragma unroll
    for (int j = 0; j < 4; j++) bfr[j] = *(const v8bf*)(Bs + (wn + j * 16 + lm) * 32 + lk);
#pragma unroll
    for (int i = 0; i < 4; i++)
#pragma unroll
      for (int j = 0; j < 4; j++)
        acc[i][j] = __builtin_amdgcn_mfma_f32_16x16x32_bf16(af[i], bfr[j], acc[i][j], 0, 0, 0);
  }
#pragma unroll
  for (int i = 0; i < 4; i++)
#pragma unroll
    for (int j = 0; j < 4; j++)
#pragma unroll
      for (int r = 0; r < 4; r++) {
        int row = mbase + wm + i * 16 + (l >> 4) * 4 + r;
        int col = nbase + wn + j * 16 + lm;
        int tok = row & 1023, bb = row >> 10;
        int i2 = col & 511;                              // PE: base 8, half=512
        float f = exp2f((float)i2 * (3.0f / 512.0f));    // 8^(i2/512)
        float a = (float)tok / f;
        float pe = (col < 512) ? sinf(a) : cosf(a);
        float v = acc[i][j][r] + bias[col] + pe;
        kvbuf[((size_t)bb * 1032 + tok) * 1024 + col] = (bf16)v;
        if (tok == 1023) lat_last[(size_t)bb * 1024 + col] = v;
      }
}

// ---------- LN (in-place on kv token rows; state rows from f32; q row from f32 lat_last) ----------
__global__ __launch_bounds__(256) void k_ln(bf16* __restrict__ kvbuf,
    const float* __restrict__ state_ws, const float* __restrict__ gkv, const float* __restrict__ bkv,
    const float* __restrict__ gq, const float* __restrict__ bq,
    float* __restrict__ qln, const float* __restrict__ lat_last) {
  int r = blockIdx.x, t = threadIdx.x, l = t & 63, w = t >> 6;
  int b = r / 1032, p = r % 1032;
  bf16* row = kvbuf + ((size_t)b * 1032 + p) * DD;
  float x[4]; float sum = 0.f, sq = 0.f;
  if (p == 1023) {
    const float* src = lat_last + (size_t)b * DD;   // full-precision latent row 1023
#pragma unroll
    for (int i = 0; i < 4; i++) {
      int j = t + i * 256;
      x[i] = src[j]; sum += x[i]; sq += x[i] * x[i];
    }
  } else if (p < 1024) {
#pragma unroll
    for (int i = 0; i < 4; i++) {
      int j = t + i * 256;
      x[i] = (float)row[j]; sum += x[i]; sq += x[i] * x[i];
    }
  } else {
    const float* src = state_ws + ((size_t)b * 8 + (p - 1024)) * DD;
#pragma unroll
    for (int i = 0; i < 4; i++) {
      int j = t + i * 256;
      x[i] = src[j]; sum += x[i]; sq += x[i] * x[i];
    }
  }
  __shared__ float sh[2][4];
  sum = wred_sum(sum); sq = wred_sum(sq);
  if (l == 0) { sh[0][w] = sum; sh[1][w] = sq; }
  __syncthreads();
  float m = (sh[0][0] + sh[0][1] + sh[0][2] + sh[0][3]) * (1.0f / 1024.0f);
  float var = (sh[1][0] + sh[1][1] + sh[1][2] + sh[1][3]) * (1.0f / 1024.0f) - m * m;
  float inv = 1.0f / sqrtf(var + LN_EPS);
  if (p == 1023) {
#pragma unroll
    for (int i = 0; i < 4; i++) {
      int j = t + i * 256;
      qln[(size_t)b * DD + j] = (x[i] - m) * inv * gq[j] + bq[j];
    }
  }
#pragma unroll
  for (int i = 0; i < 4; i++) {
    int j = t + i * 256;
    row[j] = (bf16)((x[i] - m) * inv * gkv[j] + bkv[j]);
  }
}

// ---------- LN of one f32 row per block (ffn pre-LN) ----------
__global__ __launch_bounds__(256) void k_ln_row(const float* __restrict__ src,
    const float* __restrict__ g, const float* __restrict__ bb, float* __restrict__ dst) {
  int b = blockIdx.x, t = threadIdx.x, l = t & 63, w = t >> 6;
  const float* p = src + (size_t)b * DD;
  float x[4]; float sum = 0.f, sq = 0.f;
#pragma unroll
  for (int i = 0; i < 4; i++) {
    int j = t + i * 256;
    x[i] = p[j]; sum += x[i]; sq += x[i] * x[i];
  }
  __shared__ float sh[2][4];
  sum = wred_sum(sum); sq = wred_sum(sq);
  if (l == 0) { sh[0][w] = sum; sh[1][w] = sq; }
  __syncthreads();
  float m = (sh[0][0] + sh[0][1] + sh[0][2] + sh[0][3]) * (1.0f / 1024.0f);
  float var = (sh[1][0] + sh[1][1] + sh[1][2] + sh[1][3]) * (1.0f / 1024.0f) - m * m;
  float inv = 1.0f / sqrtf(var + LN_EPS);
#pragma unroll
  for (int i = 0; i < 4; i++) {
    int j = t + i * 256;
    dst[(size_t)b * DD + j] = (x[i] - m) * inv * g[j] + bb[j];
  }
}

// ---------- attention per (b,h): u = Wk^T qp, logits = u.kv, o = Wv.(sum w kv) ----------
__global__ __launch_bounds__(256) void k_attn(const float* __restrict__ qln,
    const bf16* __restrict__ kvbuf, const float* __restrict__ Wi, const float* __restrict__ bi,
    float* __restrict__ o) {
  int b = blockIdx.x >> 3, h = blockIdx.x & 7;
  int t = threadIdx.x, l = t & 63, w = t >> 6;
  __shared__ float qp[128];
  __shared__ float u[1024];
  __shared__ float lg[1032];
  __shared__ float red[4];
  const float* qr = qln + (size_t)b * DD;
  // phase 1: q projection (head slice)
  for (int d = w; d < 128; d += 4) {
    int n = h * 128 + d;
    const float* wr = Wi + (size_t)n * DD;
    float acc = 0.f;
    for (int k = l; k < 1024; k += 64) acc += qr[k] * wr[k];
    acc = wred_sum(acc);
    if (l == 0) qp[d] = acc + bi[n];
  }
  __syncthreads();
  // phase 2: u[k] = sum_d qp[d] * Wk[h*128+d][k]; c0 = qp . bk_slice
  float uj[4] = {0.f, 0.f, 0.f, 0.f};
  const float* Wk = Wi + (size_t)1024 * DD;
  for (int d = 0; d < 128; d++) {
    const float* wr = Wk + (size_t)(h * 128 + d) * DD;
    float q = qp[d];
#pragma unroll
    for (int j = 0; j < 4; j++) uj[j] += q * wr[t + j * 256];
  }
  float c0 = 0.f;
  for (int d = 0; d < 128; d++) c0 += qp[d] * bi[1024 + h * 128 + d];
#pragma unroll
  for (int j = 0; j < 4; j++) u[t + j * 256] = uj[j];
  __syncthreads();
  // phase 3: logits over 1032 kv rows
  const float scale = 0.08838834764831845f;  // 1/sqrt(128)
  const bf16* kvb = kvbuf + (size_t)b * 1032 * DD;
  for (int p = t; p < 1032; p += 256) {
    const bf16* kr = kvb + (size_t)p * DD;
    float acc = 0.f;
    for (int k = 0; k < 1024; k += 8) {
      v8bf kv8 = *(const v8bf*)(kr + k);
#pragma unroll
      for (int q8 = 0; q8 < 8; q8++) acc += u[k + q8] * (float)kv8[q8];
    }
    lg[p] = (acc + c0) * scale;
  }
  __syncthreads();
  // phase 4: softmax
  float mx = -3.4e38f;
  for (int p = t; p < 1032; p += 256) mx = fmaxf(mx, lg[p]);
#pragma unroll
  for (int o2 = 32; o2; o2 >>= 1) mx = fmaxf(mx, __shfl_down(mx, o2, 64));
  if (l == 0) red[w] = mx;
  __syncthreads();
  mx = fmaxf(fmaxf(red[0], red[1]), fmaxf(red[2], red[3]));
  __syncthreads();
  float sume = 0.f;
  for (int p = t; p < 1032; p += 256) { float e = expf(lg[p] - mx); lg[p] = e; sume += e; }
  sume = wred_sum(sume);
  if (l == 0) red[w] = sume;
  __syncthreads();
  float invden = 1.0f / (red[0] + red[1] + red[2] + red[3]);
  // phase 5: s[k] = sum_p w_p * kv[p][k]
  float sj[4] = {0.f, 0.f, 0.f, 0.f};
  for (int p = 0; p < 1032; p++) {
    float wp = lg[p];
    const bf16* kr = kvb + (size_t)p * DD;
#pragma unroll
    for (int j = 0; j < 4; j++) sj[j] += wp * (float)kr[t + j * 256];
  }
  __syncthreads();
#pragma unroll
  for (int j = 0; j < 4; j++) u[t + j * 256] = sj[j] * invden;
  __syncthreads();
  // phase 6: o = Wv . s + bv
  const float* Wv = Wi + (size_t)2048 * DD;
  for (int d = w; d < 128; d += 4) {
    int n = h * 128 + d;
    const float* wr = Wv + (size_t)n * DD;
    float acc = 0.f;
    for (int k = l; k < 1024; k += 64) acc += u[k] * wr[k];
    acc = wred_sum(acc);
    if (l == 0) o[(size_t)b * DD + n] = acc + bi[2048 + n];
  }
}

// ---------- tail GEMVs: one wave per output element ----------
// MODE 0: out_proj + residual(lat_last)  1: fc1+gelu  2: fc2+residual  3: W_out -> f32 y
template <int MODE>
__global__ __launch_bounds__(256) void k_gemv(const float* __restrict__ xin,
    const float* __restrict__ W, const float* __restrict__ bias,
    const float* __restrict__ res, float* __restrict__ outf) {
  int idx = blockIdx.x * 4 + (threadIdx.x >> 6);
  int l = threadIdx.x & 63;
  int b = idx >> 10, n = idx & 1023;
  const float* xr = xin + (size_t)b * DD;
  const float* wr = W + (size_t)n * DD;
  float acc = 0.f;
#pragma unroll
  for (int k0 = 0; k0 < 1024; k0 += 64) acc += xr[k0 + l] * wr[k0 + l];
  acc = wred_sum(acc);
  if (l == 0) {
    float v = acc + bias[n];
    if (MODE == 0) outf[idx] = res[idx] + v;
    if (MODE == 1) outf[idx] = 0.5f * v * (1.0f + erff(v * 0.70710678118654752f));
    if (MODE == 2) outf[idx] = res[idx] + v;
    if (MODE == 3) outf[O_Y + idx] = v;
  }
}

extern "C" void kernel_launch(void* const* d_in, const int* in_sizes, int n_in,
                              void* d_out, int out_size, void* d_ws, size_t ws_size,
                              hipStream_t stream) {
  const float* x        = (const float*)d_in[0];
  const float* state_in = (const float*)d_in[1];
  const float* W_rg     = (const float*)d_in[2];
  const float* ln_moe_g = (const float*)d_in[3];
  const float* ln_moe_b = (const float*)d_in[4];
  const float* W_gate   = (const float*)d_in[5];
  const float* A_skew   = (const float*)d_in[6];
  const float* ln_sl_g  = (const float*)d_in[7];
  const float* ln_sl_b  = (const float*)d_in[8];
  const float* W_slot   = (const float*)d_in[9];
  const float* W_oe     = (const float*)d_in[10];
  const float* b_oe     = (const float*)d_in[11];
  const float* ln_q_g   = (const float*)d_in[12];
  const float* ln_q_b   = (const float*)d_in[13];
  const float* ln_kv_g  = (const float*)d_in[14];
  const float* ln_kv_b  = (const float*)d_in[15];
  const float* in_w     = (const float*)d_in[16];
  const float* in_b     = (const float*)d_in[17];
  const float* out_w    = (const float*)d_in[18];
  const float* out_b    = (const float*)d_in[19];
  const float* ln_f_g   = (const float*)d_in[20];
  const float* ln_f_b   = (const float*)d_in[21];
  const float* W_fc1    = (const float*)d_in[22];
  const float* b_fc1    = (const float*)d_in[23];
  const float* W_fc2    = (const float*)d_in[24];
  const float* b_fc2    = (const float*)d_in[25];
  const float* W_out    = (const float*)d_in[26];
  const float* b_out    = (const float*)d_in[27];

  char* ws = (char*)d_ws;
  bf16*  kvbuf    = (bf16*)(ws + W_KV);
  float* state_ws = (float*)(ws + W_STATE);
  float* lat_last = (float*)(ws + W_LATL);
  float* qln      = (float*)(ws + W_QLN);
  float* r2       = (float*)(ws + W_R2);
  float* rsc      = (float*)(ws + W_RSC);
  float* ssc      = (float*)(ws + W_SSC);
  float* o_attn   = (float*)(ws + W_OATT);
  float* lat1     = (float*)(ws + W_LAT1);
  float* lnffn    = (float*)(ws + W_LNFFN);
  float* h1       = (float*)(ws + W_H1);
  float* lat2     = (float*)(ws + W_LAT2);
  float* out = (float*)d_out;

  k_r2<<<1024, 256, 0, stream>>>(A_skew, r2);
  k_scores<<<64, 256, 0, stream>>>(state_in, W_rg, ln_sl_g, ln_sl_b, W_slot, rsc, ssc);
  k_gate<<<32, 256, 0, stream>>>(state_in, rsc, ln_moe_g, ln_moe_b, W_gate, out);
  k_state<<<8, 256, 0, stream>>>(state_in, rsc, ssc, r2, state_ws, out);
  k_gemm<<<dim3(8, 64), 256, 0, stream>>>(x, W_oe, b_oe, kvbuf, lat_last);
  k_ln<<<8256, 256, 0, stream>>>(kvbuf, state_ws, ln_kv_g, ln_kv_b, ln_q_g, ln_q_b, qln, lat_last);
  k_attn<<<64, 256, 0, stream>>>(qln, kvbuf, in_w, in_b, o_attn);
  k_gemv<0><<<2048, 256, 0, stream>>>(o_attn, out_w, out_b, lat_last, lat1);
  k_ln_row<<<8, 256, 0, stream>>>(lat1, ln_f_g, ln_f_b, lnffn);
  k_gemv<1><<<2048, 256, 0, stream>>>(lnffn, W_fc1, b_fc1, nullptr, h1);
  k_gemv<2><<<2048, 256, 0, stream>>>(h1, W_fc2, b_fc2, lat1, lat2);
  k_gemv<3><<<2048, 256, 0, stream>>>(lat2, W_out, b_out, nullptr, out);
}

// Round 8
// 567.026 us; speedup vs baseline: 14.0750x; 1.9907x over previous
//
#include <hip/hip_runtime.h>
#include <hip/hip_bf16.h>

typedef __bf16 bf16;
typedef _Float16 f16;
typedef __bf16 v8bf __attribute__((ext_vector_type(8)));
typedef float v4f __attribute__((ext_vector_type(4)));

// ---------- constants ----------
#define DD 1024
#define LN_EPS 1e-5f

// output element offsets (all f32 in d_out)
#define O_Y     0
#define O_STATE 8192
#define O_IDXE  73728
#define O_RIDX  73792
#define O_WIDX  73824

// ws byte offsets (total 17404416 B — exact round-5/7 layout, proven in-bounds)
#define W_KV      0ull                      // bf16 [8][1032][1024] 16908288
#define W_STATE   16908288ull               // f32  [8][8][1024]      262144 (PoolA: u f32 then s bf16)
#define W_LATL    17170432ull               // f32  [8][1024]          32768
#define W_QLN     17203200ull               // f32  [8][1024]  (c0[64] reuses after k_qp)
#define W_R2      17235968ull               // f32  [1024]
#define W_RSC     17240064ull               // f32  [64]
#define W_SSC     17240320ull               // f32  [64]
#define W_OATT    17240576ull               // PoolB 160KB: qp / lg(f16 132KB) / o_attn+lat1..lat2
#define W_LAT1    17273344ull
#define W_LNFFN   17306112ull
#define W_H1      17338880ull
#define W_LAT2    17371648ull

__device__ __forceinline__ float wred_sum(float v) {
#pragma unroll
  for (int o = 32; o; o >>= 1) v += __shfl_down(v, o, 64);
  return v;
}

__device__ __forceinline__ void top4_of8(const float* sc, int* ridx) {
  unsigned used = 0;
#pragma unroll
  for (int k = 0; k < 4; k++) {
    float best = -3.4e38f; int bi = 0;
    for (int s = 0; s < 8; s++)
      if (!((used >> s) & 1) && sc[s] > best) { best = sc[s]; bi = s; }
    used |= 1u << bi; ridx[k] = bi;
  }
}

// ---------- r2 = row norms of A_skew ----------
__global__ __launch_bounds__(256) void k_r2(const float* __restrict__ A, float* __restrict__ r2) {
  int row = blockIdx.x, t = threadIdx.x;
  const float* p = A + (size_t)row * DD;
  float s = 0.f;
  for (int j = t; j < DD; j += 256) { float x = p[j]; s += x * x; }
  s = wred_sum(s);
  __shared__ float sh[4];
  if ((t & 63) == 0) sh[t >> 6] = s;
  __syncthreads();
  if (t == 0) r2[row] = sh[0] + sh[1] + sh[2] + sh[3];
}

// ---------- read_scores + slot_scores ----------
__global__ __launch_bounds__(256) void k_scores(const float* __restrict__ state,
    const float* __restrict__ W_rg, const float* __restrict__ g_sl, const float* __restrict__ b_sl,
    const float* __restrict__ W_sl, float* __restrict__ rsc, float* __restrict__ ssc) {
  int row = blockIdx.x, t = threadIdx.x, l = t & 63, w = t >> 6;
  const float* p = state + (size_t)row * DD;
  float x[4]; float sum = 0.f, sq = 0.f, rs = 0.f;
#pragma unroll
  for (int i = 0; i < 4; i++) {
    int j = t + i * 256;
    x[i] = p[j];
    sum += x[i]; sq += x[i] * x[i];
    rs += x[i] * W_rg[j];
  }
  __shared__ float sh[3][4];
  sum = wred_sum(sum); sq = wred_sum(sq); rs = wred_sum(rs);
  if (l == 0) { sh[0][w] = sum; sh[1][w] = sq; sh[2][w] = rs; }
  __syncthreads();
  float m = (sh[0][0] + sh[0][1] + sh[0][2] + sh[0][3]) * (1.0f / 1024.0f);
  float var = (sh[1][0] + sh[1][1] + sh[1][2] + sh[1][3]) * (1.0f / 1024.0f) - m * m;
  float rsTot = sh[2][0] + sh[2][1] + sh[2][2] + sh[2][3];
  float inv = 1.0f / sqrtf(var + LN_EPS);
  __syncthreads();
  float ss = 0.f;
#pragma unroll
  for (int i = 0; i < 4; i++) {
    int j = t + i * 256;
    float ln = (x[i] - m) * inv * g_sl[j] + b_sl[j];
    ss += ln * W_sl[j];
  }
  ss = wred_sum(ss);
  if (l == 0) sh[0][w] = ss;
  __syncthreads();
  if (t == 0) { rsc[row] = rsTot; ssc[row] = sh[0][0] + sh[0][1] + sh[0][2] + sh[0][3]; }
}

// ---------- gate: LN_moe + gate logits + top2 -> idx_experts, read_idx (f32 out) ----------
__global__ __launch_bounds__(256) void k_gate(const float* __restrict__ state,
    const float* __restrict__ rsc, const float* __restrict__ g_moe, const float* __restrict__ b_moe,
    const float* __restrict__ Wg, float* __restrict__ out) {
  int b = blockIdx.x >> 2, k = blockIdx.x & 3;
  int t = threadIdx.x, l = t & 63, w = t >> 6;
  __shared__ float rs[8];
  __shared__ float red[2][4];
  __shared__ float gl[8];
  if (t < 8) rs[t] = rsc[b * 8 + t];
  __syncthreads();
  int ridx[4]; top4_of8(rs, ridx);
  int s = ridx[k];
  const float* p = state + (size_t)(b * 8 + s) * DD;
  float x[4]; float sum = 0.f, sq = 0.f;
#pragma unroll
  for (int i = 0; i < 4; i++) {
    int j = t + i * 256;
    x[i] = p[j]; sum += x[i]; sq += x[i] * x[i];
  }
  sum = wred_sum(sum); sq = wred_sum(sq);
  if (l == 0) { red[0][w] = sum; red[1][w] = sq; }
  __syncthreads();
  float m = (red[0][0] + red[0][1] + red[0][2] + red[0][3]) * (1.0f / 1024.0f);
  float var = (red[1][0] + red[1][1] + red[1][2] + red[1][3]) * (1.0f / 1024.0f) - m * m;
  float inv = 1.0f / sqrtf(var + LN_EPS);
  float lnv[4];
#pragma unroll
  for (int i = 0; i < 4; i++) {
    int j = t + i * 256;
    lnv[i] = (x[i] - m) * inv * g_moe[j] + b_moe[j];
  }
  __syncthreads();
  for (int e = 0; e < 8; e++) {
    float acc = 0.f;
#pragma unroll
    for (int i = 0; i < 4; i++) acc += lnv[i] * Wg[(size_t)e * DD + t + i * 256];
    acc = wred_sum(acc);
    if (l == 0) red[0][w] = acc;
    __syncthreads();
    if (t == 0) gl[e] = red[0][0] + red[0][1] + red[0][2] + red[0][3];
    __syncthreads();
  }
  if (t == 0) {
    int e0 = 0, e1 = 0; float b0 = -3.4e38f, b1 = -3.4e38f;
    for (int e = 0; e < 8; e++) {
      float v = gl[e];
      if (v > b0) { b1 = b0; e1 = e0; b0 = v; e0 = e; }
      else if (v > b1) { b1 = v; e1 = e; }
    }
    out[O_IDXE + (b * 4 + k) * 2 + 0] = (float)e0;
    out[O_IDXE + (b * 4 + k) * 2 + 1] = (float)e1;
    if (k == 0)
      for (int kk = 0; kk < 4; kk++) out[O_RIDX + b * 4 + kk] = (float)ridx[kk];
  }
}

// ---------- state update (f32 out) ----------
__global__ __launch_bounds__(256) void k_state(const float* __restrict__ state_in,
    const float* __restrict__ rsc, const float* __restrict__ ssc, const float* __restrict__ r2,
    float* __restrict__ state_ws, float* __restrict__ out) {
  int b = blockIdx.x, t = threadIdx.x;
  __shared__ float rs[8];
  if (t < 8) rs[t] = rsc[b * 8 + t];
  __syncthreads();
  int ridx[4]; top4_of8(rs, ridx);
  float lr[4];
#pragma unroll
  for (int k = 0; k < 4; k++) lr[k] = ssc[b * 8 + ridx[k]];
  int w0 = 0, w1 = 0; float b0 = -3.4e38f, b1 = -3.4e38f;
#pragma unroll
  for (int k = 0; k < 4; k++) {
    float v = lr[k];
    if (v > b0) { b1 = b0; w1 = w0; b0 = v; w0 = k; }
    else if (v > b1) { b1 = v; w1 = k; }
  }
  int wid0 = ridx[w0], wid1 = ridx[w1];
  float mx = fmaxf(lr[0], lr[1]);
  float e0 = expf(lr[0] - mx), e1 = expf(lr[1] - mx);
  float den = e0 + e1;
  float ws0 = e0 / den, ws1 = e1 / den;
  float resid = 1.0f - (ws0 + ws1);
#pragma unroll
  for (int i = 0; i < 4; i++) {
    int j = t + i * 256;
    float q = 1.0f - 0.03125f * r2[j];  // diag Cayley, c=0.125, O(c^4) dropped
    float lca = 0.f;
#pragma unroll
    for (int k = 0; k < 4; k++)
      lca += tanhf(state_in[(size_t)(b * 8 + ridx[k]) * DD + j] * q);
    float tj = tanhf(lca * 0.25f);
#pragma unroll
    for (int s = 0; s < 8; s++) {
      float a = (s == wid0) ? ws0 : ((s == wid1) ? ws1 : 0.0f);
      float v = a * tj + resid * state_in[(size_t)(b * 8 + s) * DD + j];
      state_ws[(size_t)(b * 8 + s) * DD + j] = v;
      out[O_STATE + (size_t)(b * 8 + s) * DD + j] = v;
    }
  }
  if (t == 0) {
    out[O_WIDX + b * 2 + 0] = (float)wid0;
    out[O_WIDX + b * 2 + 1] = (float)wid1;
  }
}

// ---------- MFMA BT GEMM, f32 inputs, in-register cvt + ds_write staging, XCD swizzle ----------
__global__ __launch_bounds__(256, 2) void k_gemm(const float* __restrict__ A,
    const float* __restrict__ Bm, const float* __restrict__ bias, bf16* __restrict__ kvbuf,
    float* __restrict__ lat_last) {
  __shared__ bf16 As[128 * 32];
  __shared__ bf16 Bs[128 * 32];
  const int t = threadIdx.x, l = t & 63, w = t >> 6;
  // XCD swizzle: 8 blocks sharing an A-band land on one XCD (lin%8 presumed XCD id)
  const int lin = blockIdx.y * 8 + blockIdx.x;
  const int mb = ((lin & 7) << 3) | ((lin >> 3) & 7);
  const int nb = lin >> 6;
  const int mbase = mb * 128, nbase = nb * 128;
  const int wm = (w >> 1) * 64, wn = (w & 1) * 64;
  const int lm = l & 15, lk = (l >> 4) * 8;
  v4f acc[4][4];
#pragma unroll
  for (int i = 0; i < 4; i++)
#pragma unroll
    for (int j = 0; j < 4; j++) acc[i][j] = (v4f){0.f, 0.f, 0.f, 0.f};

  const int srow = t >> 1;
  const int skc = (t & 1) * 16;
  for (int k0 = 0; k0 < 1024; k0 += 32) {
    const float* ap = A + (size_t)(mbase + srow) * 1024 + k0 + skc;
    const float* bp = Bm + (size_t)(nbase + srow) * 1024 + k0 + skc;
    float af32[16], bf32[16];
#pragma unroll
    for (int q = 0; q < 4; q++) {
      v4f va = *(const v4f*)(ap + q * 4);
      v4f vb = *(const v4f*)(bp + q * 4);
#pragma unroll
      for (int r = 0; r < 4; r++) { af32[q * 4 + r] = va[r]; bf32[q * 4 + r] = vb[r]; }
    }
    __syncthreads();
    v8bf pa, pb;
#pragma unroll
    for (int q = 0; q < 8; q++) { pa[q] = (bf16)af32[q]; pb[q] = (bf16)bf32[q]; }
    *(v8bf*)(As + srow * 32 + skc) = pa;
    *(v8bf*)(Bs + srow * 32 + skc) = pb;
#pragma unroll
    for (int q = 0; q < 8; q++) { pa[q] = (bf16)af32[8 + q]; pb[q] = (bf16)bf32[8 + q]; }
    *(v8bf*)(As + srow * 32 + skc + 8) = pa;
    *(v8bf*)(Bs + srow * 32 + skc + 8) = pb;
    __syncthreads();
    v8bf af[4], bfr[4];
#pragma unroll
    for (int i = 0; i < 4; i++) af[i] = *(const v8bf*)(As + (wm + i * 16 + lm) * 32 + lk);
#pragma unroll
    for (int j = 0; j < 4; j++) bfr[j] = *(const v8bf*)(Bs + (wn + j * 16 + lm) * 32 + lk);
#pragma unroll
    for (int i = 0; i < 4; i++)
#pragma unroll
      for (int j = 0; j < 4; j++)
        acc[i][j] = __builtin_amdgcn_mfma_f32_16x16x32_bf16(af[i], bfr[j], acc[i][j], 0, 0, 0);
  }
#pragma unroll
  for (int i = 0; i < 4; i++)
#pragma unroll
    for (int j = 0; j < 4; j++)
#pragma unroll
      for (int r = 0; r < 4; r++) {
        int row = mbase + wm + i * 16 + (l >> 4) * 4 + r;
        int col = nbase + wn + j * 16 + lm;
        int tok = row & 1023, bb = row >> 10;
        int i2 = col & 511;                              // PE: base 8, half=512
        float f = exp2f((float)i2 * (3.0f / 512.0f));    // 8^(i2/512)
        float a = (float)tok / f;
        float pe = (col < 512) ? sinf(a) : cosf(a);
        float v = acc[i][j][r] + bias[col] + pe;
        kvbuf[((size_t)bb * 1032 + tok) * 1024 + col] = (bf16)v;
        if (tok == 1023) lat_last[(size_t)bb * 1024 + col] = v;
      }
}

// ---------- LN (in-place on kv token rows; state rows from f32; q row from f32 lat_last) ----------
__global__ __launch_bounds__(256) void k_ln(bf16* __restrict__ kvbuf,
    const float* __restrict__ state_ws, const float* __restrict__ gkv, const float* __restrict__ bkv,
    const float* __restrict__ gq, const float* __restrict__ bq,
    float* __restrict__ qln, const float* __restrict__ lat_last) {
  int r = blockIdx.x, t = threadIdx.x, l = t & 63, w = t >> 6;
  int b = r / 1032, p = r % 1032;
  bf16* row = kvbuf + ((size_t)b * 1032 + p) * DD;
  float x[4]; float sum = 0.f, sq = 0.f;
  if (p == 1023) {
    const float* src = lat_last + (size_t)b * DD;
#pragma unroll
    for (int i = 0; i < 4; i++) {
      int j = t + i * 256;
      x[i] = src[j]; sum += x[i]; sq += x[i] * x[i];
    }
  } else if (p < 1024) {
#pragma unroll
    for (int i = 0; i < 4; i++) {
      int j = t + i * 256;
      x[i] = (float)row[j]; sum += x[i]; sq += x[i] * x[i];
    }
  } else {
    const float* src = state_ws + ((size_t)b * 8 + (p - 1024)) * DD;
#pragma unroll
    for (int i = 0; i < 4; i++) {
      int j = t + i * 256;
      x[i] = src[j]; sum += x[i]; sq += x[i] * x[i];
    }
  }
  __shared__ float sh[2][4];
  sum = wred_sum(sum); sq = wred_sum(sq);
  if (l == 0) { sh[0][w] = sum; sh[1][w] = sq; }
  __syncthreads();
  float m = (sh[0][0] + sh[0][1] + sh[0][2] + sh[0][3]) * (1.0f / 1024.0f);
  float var = (sh[1][0] + sh[1][1] + sh[1][2] + sh[1][3]) * (1.0f / 1024.0f) - m * m;
  float inv = 1.0f / sqrtf(var + LN_EPS);
  if (p == 1023) {
#pragma unroll
    for (int i = 0; i < 4; i++) {
      int j = t + i * 256;
      qln[(size_t)b * DD + j] = (x[i] - m) * inv * gq[j] + bq[j];
    }
  }
#pragma unroll
  for (int i = 0; i < 4; i++) {
    int j = t + i * 256;
    row[j] = (bf16)((x[i] - m) * inv * gkv[j] + bkv[j]);
  }
}

// ---------- LN of one f32 row per block (ffn pre-LN) ----------
__global__ __launch_bounds__(256) void k_ln_row(const float* __restrict__ src,
    const float* __restrict__ g, const float* __restrict__ bb, float* __restrict__ dst) {
  int b = blockIdx.x, t = threadIdx.x, l = t & 63, w = t >> 6;
  const float* p = src + (size_t)b * DD;
  float x[4]; float sum = 0.f, sq = 0.f;
#pragma unroll
  for (int i = 0; i < 4; i++) {
    int j = t + i * 256;
    x[i] = p[j]; sum += x[i]; sq += x[i] * x[i];
  }
  __shared__ float sh[2][4];
  sum = wred_sum(sum); sq = wred_sum(sq);
  if (l == 0) { sh[0][w] = sum; sh[1][w] = sq; }
  __syncthreads();
  float m = (sh[0][0] + sh[0][1] + sh[0][2] + sh[0][3]) * (1.0f / 1024.0f);
  float var = (sh[1][0] + sh[1][1] + sh[1][2] + sh[1][3]) * (1.0f / 1024.0f) - m * m;
  float inv = 1.0f / sqrtf(var + LN_EPS);
#pragma unroll
  for (int i = 0; i < 4; i++) {
    int j = t + i * 256;
    dst[(size_t)b * DD + j] = (x[i] - m) * inv * g[j] + bb[j];
  }
}

// ---------- attention pipeline ----------
// qp[b][n] = qln[b].Wq[n] + bq[n]   (2048 blocks, wave/output)
__global__ __launch_bounds__(256) void k_qp(const float* __restrict__ qln,
    const float* __restrict__ Wi, const float* __restrict__ bi, float* __restrict__ qp) {
  int idx = blockIdx.x * 4 + (threadIdx.x >> 6);
  int l = threadIdx.x & 63;
  int b = idx >> 10, n = idx & 1023;
  const float* xr = qln + (size_t)b * DD;
  const float* wr = Wi + (size_t)n * DD;
  float acc = 0.f;
#pragma unroll
  for (int k0 = 0; k0 < 1024; k0 += 64) acc += xr[k0 + l] * wr[k0 + l];
  acc = wred_sum(acc);
  if (l == 0) qp[idx] = acc + bi[n];
}

// c0[b][h] = qp[b, h-slice] . bk[h-slice]   (1 block)
__global__ __launch_bounds__(256) void k_c0(const float* __restrict__ qp,
    const float* __restrict__ bi, float* __restrict__ c0) {
  int t = threadIdx.x;
  if (t < 64) {
    int b = t >> 3, h = t & 7;
    float a = 0.f;
#pragma unroll 8
    for (int d = 0; d < 128; d++)
      a += qp[b * 1024 + h * 128 + d] * bi[1024 + h * 128 + d];
    c0[t] = a;
  }
}

// u[b][h][k] = sum_d qp[b,h*128+d] * Wk[h*128+d][k]   (grid 128 = 8h x 16 ktiles)
__global__ __launch_bounds__(256) void k_u(const float* __restrict__ qp,
    const float* __restrict__ Wi, float* __restrict__ u) {
  int h = blockIdx.x >> 4, kt = blockIdx.x & 15;
  int t = threadIdx.x;
  __shared__ float qs[8][128];
#pragma unroll
  for (int i = 0; i < 4; i++) {
    int f = t * 4 + i;            // 0..1023
    int b = f >> 7, d = f & 127;
    qs[b][d] = qp[b * 1024 + h * 128 + d];
  }
  __syncthreads();
  int k = kt * 64 + (t & 63);
  int bh = t >> 6;                // b = bh, bh+4
  const float* wkb = Wi + (size_t)(1024 + h * 128) * DD + k;
  float a0 = 0.f, a1 = 0.f;
#pragma unroll 8
  for (int d = 0; d < 128; d++) {
    float wv = wkb[(size_t)d * DD];
    a0 += qs[bh][d] * wv;
    a1 += qs[bh + 4][d] * wv;
  }
  u[(size_t)(bh * 8 + h) * DD + k] = a0;
  u[(size_t)((bh + 4) * 8 + h) * DD + k] = a1;
}

// lg[b][h][p] = (u[b,h].kv[b,p] + c0[b,h]) * scale, f16   (grid 264 = 8b x 33 ptiles of 32)
__global__ __launch_bounds__(256) void k_lg(const float* __restrict__ u,
    const bf16* __restrict__ kvbuf, const float* __restrict__ c0, f16* __restrict__ lg) {
  int b = blockIdx.x / 33, tile = blockIdx.x % 33;
  int p0 = tile * 32, t = threadIdx.x;
  __shared__ bf16 kvs[32 * 1032];     // row stride 1032 (pad 8) -> conflict-free v8bf reads
  __shared__ float us[8 * 1032];      // row stride 1032 -> conflict-free v4f-class reads
  const bf16* kvb = kvbuf + (size_t)b * 1032 * DD;
#pragma unroll
  for (int i = 0; i < 16; i++) {      // 4096 v8bf chunks of kv tile
    int flat = (i * 256 + t) * 8;
    int row = flat >> 10, col = flat & 1023;
    int gp = p0 + row; if (gp > 1031) gp = 1031;
    *(v8bf*)(kvs + row * 1032 + col) = *(const v8bf*)(kvb + (size_t)gp * DD + col);
  }
#pragma unroll
  for (int i = 0; i < 8; i++) {       // 2048 v4f chunks of u[b]
    int flat = (i * 256 + t) * 4;
    int row = flat >> 10, col = flat & 1023;
    *(v4f*)(us + row * 1032 + col) = *(const v4f*)(u + (size_t)(b * 8 + row) * DD + col);
  }
  __syncthreads();
  int pl = t >> 3, h = t & 7;
  if (p0 + pl < 1032) {
    float acc = 0.f;
#pragma unroll
    for (int k = 0; k < 1024; k += 8) {
      v8bf kv8 = *(const v8bf*)(kvs + pl * 1032 + k);
#pragma unroll
      for (int j = 0; j < 8; j++) acc += us[h * 1032 + k + j] * (float)kv8[j];
    }
    lg[(size_t)(b * 8 + h) * 1032 + p0 + pl] =
        (f16)((acc + c0[b * 8 + h]) * 0.08838834764831845f);
  }
}

// softmax in place on lg[bh][1032]   (64 blocks)
__global__ __launch_bounds__(256) void k_sm(f16* __restrict__ lg) {
  int t = threadIdx.x, l = t & 63, w = t >> 6;
  f16* p = lg + (size_t)blockIdx.x * 1032;
  float x[5];
  float mx = -3.4e38f;
#pragma unroll
  for (int i = 0; i < 5; i++) {
    int idx = t + i * 256;
    if (idx < 1032) { x[i] = (float)p[idx]; mx = fmaxf(mx, x[i]); }
  }
  __shared__ float sh[4];
#pragma unroll
  for (int o = 32; o; o >>= 1) mx = fmaxf(mx, __shfl_down(mx, o, 64));
  if (l == 0) sh[w] = mx;
  __syncthreads();
  mx = fmaxf(fmaxf(sh[0], sh[1]), fmaxf(sh[2], sh[3]));
  __syncthreads();
  float sum = 0.f;
#pragma unroll
  for (int i = 0; i < 5; i++) {
    int idx = t + i * 256;
    if (idx < 1032) { x[i] = expf(x[i] - mx); sum += x[i]; }
  }
  sum = wred_sum(sum);
  if (l == 0) sh[w] = sum;
  __syncthreads();
  float inv = 1.0f / (sh[0] + sh[1] + sh[2] + sh[3]);
#pragma unroll
  for (int i = 0; i < 5; i++) {
    int idx = t + i * 256;
    if (idx < 1032) p[idx] = (f16)(x[i] * inv);
  }
}

// s[b][h][k] = sum_p w[b,h,p] * kv[b,p,k], bf16   (grid 128 = 8b x 16 ktiles of 64)
__global__ __launch_bounds__(256) void k_s(const f16* __restrict__ lg,
    const bf16* __restrict__ kvbuf, bf16* __restrict__ s) {
  int b = blockIdx.x >> 4, kt = blockIdx.x & 15;
  int t = threadIdx.x;
  __shared__ f16 wl[8 * 1040];
  for (int h = 0; h < 8; h++)
    for (int i = t; i < 1032; i += 256)
      wl[h * 1040 + i] = lg[(size_t)(b * 8 + h) * 1032 + i];
  __syncthreads();
  int k = kt * 64 + (t & 63), h0 = t >> 6;
  const bf16* kvb = kvbuf + (size_t)b * 1032 * DD + k;
  float a0 = 0.f, a1 = 0.f;
#pragma unroll 4
  for (int p = 0; p < 1032; p++) {
    float kvv = (float)kvb[(size_t)p * DD];
    a0 += (float)wl[h0 * 1040 + p] * kvv;
    a1 += (float)wl[(h0 + 4) * 1040 + p] * kvv;
  }
  s[(size_t)(b * 8 + h0) * DD + k] = (bf16)a0;
  s[(size_t)(b * 8 + h0 + 4) * DD + k] = (bf16)a1;
}

// o_attn[b][n] = Wv[n] . s[b, n>>7] + bv[n]   (2048 blocks, wave/output)
__global__ __launch_bounds__(256) void k_ov(const bf16* __restrict__ s,
    const float* __restrict__ Wi, const float* __restrict__ bi, float* __restrict__ o) {
  int idx = blockIdx.x * 4 + (threadIdx.x >> 6);
  int l = threadIdx.x & 63;
  int b = idx >> 10, n = idx & 1023, h = n >> 7;
  const bf16* sr = s + (size_t)(b * 8 + h) * DD;
  const float* wr = Wi + (size_t)(2048 + n) * DD;
  float acc = 0.f;
#pragma unroll
  for (int k0 = 0; k0 < 1024; k0 += 64) acc += (float)sr[k0 + l] * wr[k0 + l];
  acc = wred_sum(acc);
  if (l == 0) o[idx] = acc + bi[2048 + n];
}

// ---------- tail GEMVs ----------
// MODE 0: out_proj + residual(lat_last)  1: fc1+gelu  2: fc2+residual  3: W_out -> f32 y
template <int MODE>
__global__ __launch_bounds__(256) void k_gemv(const float* __restrict__ xin,
    const float* __restrict__ W, const float* __restrict__ bias,
    const float* __restrict__ res, float* __restrict__ outf) {
  int idx = blockIdx.x * 4 + (threadIdx.x >> 6);
  int l = threadIdx.x & 63;
  int b = idx >> 10, n = idx & 1023;
  const float* xr = xin + (size_t)b * DD;
  const float* wr = W + (size_t)n * DD;
  float acc = 0.f;
#pragma unroll
  for (int k0 = 0; k0 < 1024; k0 += 64) acc += xr[k0 + l] * wr[k0 + l];
  acc = wred_sum(acc);
  if (l == 0) {
    float v = acc + bias[n];
    if (MODE == 0) outf[idx] = res[idx] + v;
    if (MODE == 1) outf[idx] = 0.5f * v * (1.0f + erff(v * 0.70710678118654752f));
    if (MODE == 2) outf[idx] = res[idx] + v;
    if (MODE == 3) outf[O_Y + idx] = v;
  }
}

extern "C" void kernel_launch(void* const* d_in, const int* in_sizes, int n_in,
                              void* d_out, int out_size, void* d_ws, size_t ws_size,
                              hipStream_t stream) {
  const float* x        = (const float*)d_in[0];
  const float* state_in = (const float*)d_in[1];
  const float* W_rg     = (const float*)d_in[2];
  const float* ln_moe_g = (const float*)d_in[3];
  const float* ln_moe_b = (const float*)d_in[4];
  const float* W_gate   = (const float*)d_in[5];
  const float* A_skew   = (const float*)d_in[6];
  const float* ln_sl_g  = (const float*)d_in[7];
  const float* ln_sl_b  = (const float*)d_in[8];
  const float* W_slot   = (const float*)d_in[9];
  const float* W_oe     = (const float*)d_in[10];
  const float* b_oe     = (const float*)d_in[11];
  const float* ln_q_g   = (const float*)d_in[12];
  const float* ln_q_b   = (const float*)d_in[13];
  const float* ln_kv_g  = (const float*)d_in[14];
  const float* ln_kv_b  = (const float*)d_in[15];
  const float* in_w     = (const float*)d_in[16];
  const float* in_b     = (const float*)d_in[17];
  const float* out_w    = (const float*)d_in[18];
  const float* out_b    = (const float*)d_in[19];
  const float* ln_f_g   = (const float*)d_in[20];
  const float* ln_f_b   = (const float*)d_in[21];
  const float* W_fc1    = (const float*)d_in[22];
  const float* b_fc1    = (const float*)d_in[23];
  const float* W_fc2    = (const float*)d_in[24];
  const float* b_fc2    = (const float*)d_in[25];
  const float* W_out    = (const float*)d_in[26];
  const float* b_out    = (const float*)d_in[27];

  char* ws = (char*)d_ws;
  bf16*  kvbuf    = (bf16*)(ws + W_KV);
  float* state_ws = (float*)(ws + W_STATE);     // PoolA: later u (f32), then s (bf16)
  float* u_buf    = (float*)(ws + W_STATE);
  bf16*  s_buf    = (bf16*)(ws + W_STATE);
  float* lat_last = (float*)(ws + W_LATL);
  float* qln      = (float*)(ws + W_QLN);
  float* c0       = (float*)(ws + W_QLN);       // reuses qln after k_qp consumed it
  float* r2       = (float*)(ws + W_R2);
  float* rsc      = (float*)(ws + W_RSC);
  float* ssc      = (float*)(ws + W_SSC);
  float* qp       = (float*)(ws + W_OATT);      // PoolB: qp -> lg -> o_attn/lat1..
  f16*   lg       = (f16*)(ws + W_OATT);
  float* o_attn   = (float*)(ws + W_OATT);
  float* lat1     = (float*)(ws + W_LAT1);
  float* lnffn    = (float*)(ws + W_LNFFN);
  float* h1       = (float*)(ws + W_H1);
  float* lat2     = (float*)(ws + W_LAT2);
  float* out = (float*)d_out;

  k_r2<<<1024, 256, 0, stream>>>(A_skew, r2);
  k_scores<<<64, 256, 0, stream>>>(state_in, W_rg, ln_sl_g, ln_sl_b, W_slot, rsc, ssc);
  k_gate<<<32, 256, 0, stream>>>(state_in, rsc, ln_moe_g, ln_moe_b, W_gate, out);
  k_state<<<8, 256, 0, stream>>>(state_in, rsc, ssc, r2, state_ws, out);
  k_gemm<<<dim3(8, 64), 256, 0, stream>>>(x, W_oe, b_oe, kvbuf, lat_last);
  k_ln<<<8256, 256, 0, stream>>>(kvbuf, state_ws, ln_kv_g, ln_kv_b, ln_q_g, ln_q_b, qln, lat_last);
  k_qp<<<2048, 256, 0, stream>>>(qln, in_w, in_b, qp);
  k_c0<<<1, 256, 0, stream>>>(qp, in_b, c0);           // c0 overwrites qln (dead)
  k_u<<<128, 256, 0, stream>>>(qp, in_w, u_buf);       // u overwrites state_ws (dead)
  k_lg<<<264, 256, 0, stream>>>(u_buf, kvbuf, c0, lg); // lg overwrites qp (dead)
  k_sm<<<64, 256, 0, stream>>>(lg);
  k_s<<<128, 256, 0, stream>>>(lg, kvbuf, s_buf);      // s overwrites u (dead)
  k_ov<<<2048, 256, 0, stream>>>(s_buf, in_w, in_b, o_attn);  // overwrites lg head (dead)
  k_gemv<0><<<2048, 256, 0, stream>>>(o_attn, out_w, out_b, lat_last, lat1);
  k_ln_row<<<8, 256, 0, stream>>>(lat1, ln_f_g, ln_f_b, lnffn);
  k_gemv<1><<<2048, 256, 0, stream>>>(lnffn, W_fc1, b_fc1, nullptr, h1);
  k_gemv<2><<<2048, 256, 0, stream>>>(h1, W_fc2, b_fc2, lat1, lat2);
  k_gemv<3><<<2048, 256, 0, stream>>>(lat2, W_out, b_out, nullptr, out);
}

// Round 9
// 561.347 us; speedup vs baseline: 14.2174x; 1.0101x over previous
//
#include <hip/hip_runtime.h>
#include <hip/hip_bf16.h>

typedef __bf16 bf16;
typedef _Float16 f16;
typedef __bf16 v8bf __attribute__((ext_vector_type(8)));
typedef float v4f __attribute__((ext_vector_type(4)));

// ---------- constants ----------
#define DD 1024
#define LN_EPS 1e-5f

// output element offsets (all f32 in d_out)
#define O_Y     0
#define O_STATE 8192
#define O_IDXE  73728
#define O_RIDX  73792
#define O_WIDX  73824

// ws byte offsets (total 17404416 B — exact round-5/7 layout, proven in-bounds)
#define W_KV      0ull                      // bf16 [8][1032][1024] 16908288
#define W_STATE   16908288ull               // f32  [8][8][1024]      262144 (PoolA: u f32 then s bf16)
#define W_LATL    17170432ull               // f32  [8][1024]          32768
#define W_QLN     17203200ull               // f32  [8][1024]  (c0[64] reuses after k_qp)
#define W_R2      17235968ull               // f32  [1024]
#define W_RSC     17240064ull               // f32  [64]
#define W_SSC     17240320ull               // f32  [64]
#define W_OATT    17240576ull               // PoolB 160KB: qp / lg(f16 132KB) / o_attn+lat1..lat2
#define W_LAT1    17273344ull
#define W_LNFFN   17306112ull
#define W_H1      17338880ull
#define W_LAT2    17371648ull

__device__ __forceinline__ float wred_sum(float v) {
#pragma unroll
  for (int o = 32; o; o >>= 1) v += __shfl_down(v, o, 64);
  return v;
}

__device__ __forceinline__ void top4_of8(const float* sc, int* ridx) {
  unsigned used = 0;
#pragma unroll
  for (int k = 0; k < 4; k++) {
    float best = -3.4e38f; int bi = 0;
    for (int s = 0; s < 8; s++)
      if (!((used >> s) & 1) && sc[s] > best) { best = sc[s]; bi = s; }
    used |= 1u << bi; ridx[k] = bi;
  }
}

// ---------- r2 = row norms of A_skew ----------
__global__ __launch_bounds__(256) void k_r2(const float* __restrict__ A, float* __restrict__ r2) {
  int row = blockIdx.x, t = threadIdx.x;
  const float* p = A + (size_t)row * DD;
  float s = 0.f;
  for (int j = t; j < DD; j += 256) { float x = p[j]; s += x * x; }
  s = wred_sum(s);
  __shared__ float sh[4];
  if ((t & 63) == 0) sh[t >> 6] = s;
  __syncthreads();
  if (t == 0) r2[row] = sh[0] + sh[1] + sh[2] + sh[3];
}

// ---------- read_scores + slot_scores ----------
__global__ __launch_bounds__(256) void k_scores(const float* __restrict__ state,
    const float* __restrict__ W_rg, const float* __restrict__ g_sl, const float* __restrict__ b_sl,
    const float* __restrict__ W_sl, float* __restrict__ rsc, float* __restrict__ ssc) {
  int row = blockIdx.x, t = threadIdx.x, l = t & 63, w = t >> 6;
  const float* p = state + (size_t)row * DD;
  float x[4]; float sum = 0.f, sq = 0.f, rs = 0.f;
#pragma unroll
  for (int i = 0; i < 4; i++) {
    int j = t + i * 256;
    x[i] = p[j];
    sum += x[i]; sq += x[i] * x[i];
    rs += x[i] * W_rg[j];
  }
  __shared__ float sh[3][4];
  sum = wred_sum(sum); sq = wred_sum(sq); rs = wred_sum(rs);
  if (l == 0) { sh[0][w] = sum; sh[1][w] = sq; sh[2][w] = rs; }
  __syncthreads();
  float m = (sh[0][0] + sh[0][1] + sh[0][2] + sh[0][3]) * (1.0f / 1024.0f);
  float var = (sh[1][0] + sh[1][1] + sh[1][2] + sh[1][3]) * (1.0f / 1024.0f) - m * m;
  float rsTot = sh[2][0] + sh[2][1] + sh[2][2] + sh[2][3];
  float inv = 1.0f / sqrtf(var + LN_EPS);
  __syncthreads();
  float ss = 0.f;
#pragma unroll
  for (int i = 0; i < 4; i++) {
    int j = t + i * 256;
    float ln = (x[i] - m) * inv * g_sl[j] + b_sl[j];
    ss += ln * W_sl[j];
  }
  ss = wred_sum(ss);
  if (l == 0) sh[0][w] = ss;
  __syncthreads();
  if (t == 0) { rsc[row] = rsTot; ssc[row] = sh[0][0] + sh[0][1] + sh[0][2] + sh[0][3]; }
}

// ---------- gate: LN_moe + gate logits + top2 -> idx_experts, read_idx (f32 out) ----------
__global__ __launch_bounds__(256) void k_gate(const float* __restrict__ state,
    const float* __restrict__ rsc, const float* __restrict__ g_moe, const float* __restrict__ b_moe,
    const float* __restrict__ Wg, float* __restrict__ out) {
  int b = blockIdx.x >> 2, k = blockIdx.x & 3;
  int t = threadIdx.x, l = t & 63, w = t >> 6;
  __shared__ float rs[8];
  __shared__ float red[2][4];
  __shared__ float gl[8];
  if (t < 8) rs[t] = rsc[b * 8 + t];
  __syncthreads();
  int ridx[4]; top4_of8(rs, ridx);
  int s = ridx[k];
  const float* p = state + (size_t)(b * 8 + s) * DD;
  float x[4]; float sum = 0.f, sq = 0.f;
#pragma unroll
  for (int i = 0; i < 4; i++) {
    int j = t + i * 256;
    x[i] = p[j]; sum += x[i]; sq += x[i] * x[i];
  }
  sum = wred_sum(sum); sq = wred_sum(sq);
  if (l == 0) { red[0][w] = sum; red[1][w] = sq; }
  __syncthreads();
  float m = (red[0][0] + red[0][1] + red[0][2] + red[0][3]) * (1.0f / 1024.0f);
  float var = (red[1][0] + red[1][1] + red[1][2] + red[1][3]) * (1.0f / 1024.0f) - m * m;
  float inv = 1.0f / sqrtf(var + LN_EPS);
  float lnv[4];
#pragma unroll
  for (int i = 0; i < 4; i++) {
    int j = t + i * 256;
    lnv[i] = (x[i] - m) * inv * g_moe[j] + b_moe[j];
  }
  __syncthreads();
  for (int e = 0; e < 8; e++) {
    float acc = 0.f;
#pragma unroll
    for (int i = 0; i < 4; i++) acc += lnv[i] * Wg[(size_t)e * DD + t + i * 256];
    acc = wred_sum(acc);
    if (l == 0) red[0][w] = acc;
    __syncthreads();
    if (t == 0) gl[e] = red[0][0] + red[0][1] + red[0][2] + red[0][3];
    __syncthreads();
  }
  if (t == 0) {
    int e0 = 0, e1 = 0; float b0 = -3.4e38f, b1 = -3.4e38f;
    for (int e = 0; e < 8; e++) {
      float v = gl[e];
      if (v > b0) { b1 = b0; e1 = e0; b0 = v; e0 = e; }
      else if (v > b1) { b1 = v; e1 = e; }
    }
    out[O_IDXE + (b * 4 + k) * 2 + 0] = (float)e0;
    out[O_IDXE + (b * 4 + k) * 2 + 1] = (float)e1;
    if (k == 0)
      for (int kk = 0; kk < 4; kk++) out[O_RIDX + b * 4 + kk] = (float)ridx[kk];
  }
}

// ---------- state update (f32 out) ----------
__global__ __launch_bounds__(256) void k_state(const float* __restrict__ state_in,
    const float* __restrict__ rsc, const float* __restrict__ ssc, const float* __restrict__ r2,
    float* __restrict__ state_ws, float* __restrict__ out) {
  int b = blockIdx.x, t = threadIdx.x;
  __shared__ float rs[8];
  if (t < 8) rs[t] = rsc[b * 8 + t];
  __syncthreads();
  int ridx[4]; top4_of8(rs, ridx);
  float lr[4];
#pragma unroll
  for (int k = 0; k < 4; k++) lr[k] = ssc[b * 8 + ridx[k]];
  int w0 = 0, w1 = 0; float b0 = -3.4e38f, b1 = -3.4e38f;
#pragma unroll
  for (int k = 0; k < 4; k++) {
    float v = lr[k];
    if (v > b0) { b1 = b0; w1 = w0; b0 = v; w0 = k; }
    else if (v > b1) { b1 = v; w1 = k; }
  }
  int wid0 = ridx[w0], wid1 = ridx[w1];
  float mx = fmaxf(lr[0], lr[1]);
  float e0 = expf(lr[0] - mx), e1 = expf(lr[1] - mx);
  float den = e0 + e1;
  float ws0 = e0 / den, ws1 = e1 / den;
  float resid = 1.0f - (ws0 + ws1);
#pragma unroll
  for (int i = 0; i < 4; i++) {
    int j = t + i * 256;
    float q = 1.0f - 0.03125f * r2[j];  // diag Cayley, c=0.125, O(c^4) dropped
    float lca = 0.f;
#pragma unroll
    for (int k = 0; k < 4; k++)
      lca += tanhf(state_in[(size_t)(b * 8 + ridx[k]) * DD + j] * q);
    float tj = tanhf(lca * 0.25f);
#pragma unroll
    for (int s = 0; s < 8; s++) {
      float a = (s == wid0) ? ws0 : ((s == wid1) ? ws1 : 0.0f);
      float v = a * tj + resid * state_in[(size_t)(b * 8 + s) * DD + j];
      state_ws[(size_t)(b * 8 + s) * DD + j] = v;
      out[O_STATE + (size_t)(b * 8 + s) * DD + j] = v;
    }
  }
  if (t == 0) {
    out[O_WIDX + b * 2 + 0] = (float)wid0;
    out[O_WIDX + b * 2 + 1] = (float)wid1;
  }
}

// ---------- MFMA BT GEMM, f32 inputs, register-lean cvt staging, XCD swizzle ----------
// Thread t stages rows (t>>2) and (t>>2)+64, k-cols (t&3)*8..+7 -> LDS byte offset 16*t
// and 16*t+4096: perfectly linear, conflict-free.
__global__ __launch_bounds__(256) void k_gemm(const float* __restrict__ A,
    const float* __restrict__ Bm, const float* __restrict__ bias, bf16* __restrict__ kvbuf,
    float* __restrict__ lat_last) {
  __shared__ bf16 As[128 * 32];
  __shared__ bf16 Bs[128 * 32];
  const int t = threadIdx.x, l = t & 63, w = t >> 6;
  const int lin = blockIdx.y * 8 + blockIdx.x;
  const int mb = ((lin & 7) << 3) | ((lin >> 3) & 7);   // 8 A-band blocks per XCD
  const int nb = lin >> 6;
  const int mbase = mb * 128, nbase = nb * 128;
  const int wm = (w >> 1) * 64, wn = (w & 1) * 64;
  const int lm = l & 15, lk = (l >> 4) * 8;
  v4f acc[4][4];
#pragma unroll
  for (int i = 0; i < 4; i++)
#pragma unroll
    for (int j = 0; j < 4; j++) acc[i][j] = (v4f){0.f, 0.f, 0.f, 0.f};

  const int srow = t >> 2;          // 0..63
  const int skc = (t & 3) * 8;      // 0,8,16,24 (elements within BK=32)
  for (int k0 = 0; k0 < 1024; k0 += 32) {
    const float* ap0 = A + (size_t)(mbase + srow) * 1024 + k0 + skc;
    const float* ap1 = ap0 + (size_t)64 * 1024;
    const float* bp0 = Bm + (size_t)(nbase + srow) * 1024 + k0 + skc;
    const float* bp1 = bp0 + (size_t)64 * 1024;
    // named v4f registers — un-spillable, loads overlap previous iter's MFMA
    v4f a00 = *(const v4f*)ap0, a01 = *(const v4f*)(ap0 + 4);
    v4f a10 = *(const v4f*)ap1, a11 = *(const v4f*)(ap1 + 4);
    v4f b00 = *(const v4f*)bp0, b01 = *(const v4f*)(bp0 + 4);
    v4f b10 = *(const v4f*)bp1, b11 = *(const v4f*)(bp1 + 4);
    __syncthreads();
    v8bf pk;
#pragma unroll
    for (int r = 0; r < 4; r++) { pk[r] = (bf16)a00[r]; pk[4 + r] = (bf16)a01[r]; }
    *(v8bf*)(As + srow * 32 + skc) = pk;
#pragma unroll
    for (int r = 0; r < 4; r++) { pk[r] = (bf16)a10[r]; pk[4 + r] = (bf16)a11[r]; }
    *(v8bf*)(As + (srow + 64) * 32 + skc) = pk;
#pragma unroll
    for (int r = 0; r < 4; r++) { pk[r] = (bf16)b00[r]; pk[4 + r] = (bf16)b01[r]; }
    *(v8bf*)(Bs + srow * 32 + skc) = pk;
#pragma unroll
    for (int r = 0; r < 4; r++) { pk[r] = (bf16)b10[r]; pk[4 + r] = (bf16)b11[r]; }
    *(v8bf*)(Bs + (srow + 64) * 32 + skc) = pk;
    __syncthreads();
    v8bf af[4], bfr[4];
#pragma unroll
    for (int i = 0; i < 4; i++) af[i] = *(const v8bf*)(As + (wm + i * 16 + lm) * 32 + lk);
#pragma unroll
    for (int j = 0; j < 4; j++) bfr[j] = *(const v8bf*)(Bs + (wn + j * 16 + lm) * 32 + lk);
#pragma unroll
    for (int i = 0; i < 4; i++)
#pragma unroll
      for (int j = 0; j < 4; j++)
        acc[i][j] = __builtin_amdgcn_mfma_f32_16x16x32_bf16(af[i], bfr[j], acc[i][j], 0, 0, 0);
  }
#pragma unroll
  for (int i = 0; i < 4; i++)
#pragma unroll
    for (int j = 0; j < 4; j++)
#pragma unroll
      for (int r = 0; r < 4; r++) {
        int row = mbase + wm + i * 16 + (l >> 4) * 4 + r;
        int col = nbase + wn + j * 16 + lm;
        int tok = row & 1023, bb = row >> 10;
        int i2 = col & 511;                              // PE: base 8, half=512
        float f = exp2f((float)i2 * (3.0f / 512.0f));    // 8^(i2/512)
        float a = (float)tok / f;
        float pe = (col < 512) ? sinf(a) : cosf(a);
        float v = acc[i][j][r] + bias[col] + pe;
        kvbuf[((size_t)bb * 1032 + tok) * 1024 + col] = (bf16)v;
        if (tok == 1023) lat_last[(size_t)bb * 1024 + col] = v;
      }
}

// ---------- LN (in-place on kv token rows; state rows from f32; q row from f32 lat_last) ----------
__global__ __launch_bounds__(256) void k_ln(bf16* __restrict__ kvbuf,
    const float* __restrict__ state_ws, const float* __restrict__ gkv, const float* __restrict__ bkv,
    const float* __restrict__ gq, const float* __restrict__ bq,
    float* __restrict__ qln, const float* __restrict__ lat_last) {
  int r = blockIdx.x, t = threadIdx.x, l = t & 63, w = t >> 6;
  int b = r / 1032, p = r % 1032;
  bf16* row = kvbuf + ((size_t)b * 1032 + p) * DD;
  float x[4]; float sum = 0.f, sq = 0.f;
  if (p == 1023) {
    const float* src = lat_last + (size_t)b * DD;
#pragma unroll
    for (int i = 0; i < 4; i++) {
      int j = t + i * 256;
      x[i] = src[j]; sum += x[i]; sq += x[i] * x[i];
    }
  } else if (p < 1024) {
#pragma unroll
    for (int i = 0; i < 4; i++) {
      int j = t + i * 256;
      x[i] = (float)row[j]; sum += x[i]; sq += x[i] * x[i];
    }
  } else {
    const float* src = state_ws + ((size_t)b * 8 + (p - 1024)) * DD;
#pragma unroll
    for (int i = 0; i < 4; i++) {
      int j = t + i * 256;
      x[i] = src[j]; sum += x[i]; sq += x[i] * x[i];
    }
  }
  __shared__ float sh[2][4];
  sum = wred_sum(sum); sq = wred_sum(sq);
  if (l == 0) { sh[0][w] = sum; sh[1][w] = sq; }
  __syncthreads();
  float m = (sh[0][0] + sh[0][1] + sh[0][2] + sh[0][3]) * (1.0f / 1024.0f);
  float var = (sh[1][0] + sh[1][1] + sh[1][2] + sh[1][3]) * (1.0f / 1024.0f) - m * m;
  float inv = 1.0f / sqrtf(var + LN_EPS);
  if (p == 1023) {
#pragma unroll
    for (int i = 0; i < 4; i++) {
      int j = t + i * 256;
      qln[(size_t)b * DD + j] = (x[i] - m) * inv * gq[j] + bq[j];
    }
  }
#pragma unroll
  for (int i = 0; i < 4; i++) {
    int j = t + i * 256;
    row[j] = (bf16)((x[i] - m) * inv * gkv[j] + bkv[j]);
  }
}

// ---------- LN of one f32 row per block (ffn pre-LN) ----------
__global__ __launch_bounds__(256) void k_ln_row(const float* __restrict__ src,
    const float* __restrict__ g, const float* __restrict__ bb, float* __restrict__ dst) {
  int b = blockIdx.x, t = threadIdx.x, l = t & 63, w = t >> 6;
  const float* p = src + (size_t)b * DD;
  float x[4]; float sum = 0.f, sq = 0.f;
#pragma unroll
  for (int i = 0; i < 4; i++) {
    int j = t + i * 256;
    x[i] = p[j]; sum += x[i]; sq += x[i] * x[i];
  }
  __shared__ float sh[2][4];
  sum = wred_sum(sum); sq = wred_sum(sq);
  if (l == 0) { sh[0][w] = sum; sh[1][w] = sq; }
  __syncthreads();
  float m = (sh[0][0] + sh[0][1] + sh[0][2] + sh[0][3]) * (1.0f / 1024.0f);
  float var = (sh[1][0] + sh[1][1] + sh[1][2] + sh[1][3]) * (1.0f / 1024.0f) - m * m;
  float inv = 1.0f / sqrtf(var + LN_EPS);
#pragma unroll
  for (int i = 0; i < 4; i++) {
    int j = t + i * 256;
    dst[(size_t)b * DD + j] = (x[i] - m) * inv * g[j] + bb[j];
  }
}

// ---------- attention pipeline ----------
__global__ __launch_bounds__(256) void k_qp(const float* __restrict__ qln,
    const float* __restrict__ Wi, const float* __restrict__ bi, float* __restrict__ qp) {
  int idx = blockIdx.x * 4 + (threadIdx.x >> 6);
  int l = threadIdx.x & 63;
  int b = idx >> 10, n = idx & 1023;
  const float* xr = qln + (size_t)b * DD;
  const float* wr = Wi + (size_t)n * DD;
  float acc = 0.f;
#pragma unroll
  for (int k0 = 0; k0 < 1024; k0 += 64) acc += xr[k0 + l] * wr[k0 + l];
  acc = wred_sum(acc);
  if (l == 0) qp[idx] = acc + bi[n];
}

__global__ __launch_bounds__(256) void k_c0(const float* __restrict__ qp,
    const float* __restrict__ bi, float* __restrict__ c0) {
  int t = threadIdx.x;
  if (t < 64) {
    int b = t >> 3, h = t & 7;
    float a = 0.f;
#pragma unroll 8
    for (int d = 0; d < 128; d++)
      a += qp[b * 1024 + h * 128 + d] * bi[1024 + h * 128 + d];
    c0[t] = a;
  }
}

__global__ __launch_bounds__(256) void k_u(const float* __restrict__ qp,
    const float* __restrict__ Wi, float* __restrict__ u) {
  int h = blockIdx.x >> 4, kt = blockIdx.x & 15;
  int t = threadIdx.x;
  __shared__ float qs[8][128];
#pragma unroll
  for (int i = 0; i < 4; i++) {
    int f = t * 4 + i;
    int b = f >> 7, d = f & 127;
    qs[b][d] = qp[b * 1024 + h * 128 + d];
  }
  __syncthreads();
  int k = kt * 64 + (t & 63);
  int bh = t >> 6;
  const float* wkb = Wi + (size_t)(1024 + h * 128) * DD + k;
  float a0 = 0.f, a1 = 0.f;
#pragma unroll 8
  for (int d = 0; d < 128; d++) {
    float wv = wkb[(size_t)d * DD];
    a0 += qs[bh][d] * wv;
    a1 += qs[bh + 4][d] * wv;
  }
  u[(size_t)(bh * 8 + h) * DD + k] = a0;
  u[(size_t)((bh + 4) * 8 + h) * DD + k] = a1;
}

__global__ __launch_bounds__(256) void k_lg(const float* __restrict__ u,
    const bf16* __restrict__ kvbuf, const float* __restrict__ c0, f16* __restrict__ lg) {
  int b = blockIdx.x / 33, tile = blockIdx.x % 33;
  int p0 = tile * 32, t = threadIdx.x;
  __shared__ bf16 kvs[32 * 1032];
  __shared__ float us[8 * 1032];
  const bf16* kvb = kvbuf + (size_t)b * 1032 * DD;
#pragma unroll
  for (int i = 0; i < 16; i++) {
    int flat = (i * 256 + t) * 8;
    int row = flat >> 10, col = flat & 1023;
    int gp = p0 + row; if (gp > 1031) gp = 1031;
    *(v8bf*)(kvs + row * 1032 + col) = *(const v8bf*)(kvb + (size_t)gp * DD + col);
  }
#pragma unroll
  for (int i = 0; i < 8; i++) {
    int flat = (i * 256 + t) * 4;
    int row = flat >> 10, col = flat & 1023;
    *(v4f*)(us + row * 1032 + col) = *(const v4f*)(u + (size_t)(b * 8 + row) * DD + col);
  }
  __syncthreads();
  int pl = t >> 3, h = t & 7;
  if (p0 + pl < 1032) {
    float acc = 0.f;
#pragma unroll
    for (int k = 0; k < 1024; k += 8) {
      v8bf kv8 = *(const v8bf*)(kvs + pl * 1032 + k);
#pragma unroll
      for (int j = 0; j < 8; j++) acc += us[h * 1032 + k + j] * (float)kv8[j];
    }
    lg[(size_t)(b * 8 + h) * 1032 + p0 + pl] =
        (f16)((acc + c0[b * 8 + h]) * 0.08838834764831845f);
  }
}

__global__ __launch_bounds__(256) void k_sm(f16* __restrict__ lg) {
  int t = threadIdx.x, l = t & 63, w = t >> 6;
  f16* p = lg + (size_t)blockIdx.x * 1032;
  float x[5];
  float mx = -3.4e38f;
#pragma unroll
  for (int i = 0; i < 5; i++) {
    int idx = t + i * 256;
    if (idx < 1032) { x[i] = (float)p[idx]; mx = fmaxf(mx, x[i]); }
  }
  __shared__ float sh[4];
#pragma unroll
  for (int o = 32; o; o >>= 1) mx = fmaxf(mx, __shfl_down(mx, o, 64));
  if (l == 0) sh[w] = mx;
  __syncthreads();
  mx = fmaxf(fmaxf(sh[0], sh[1]), fmaxf(sh[2], sh[3]));
  __syncthreads();
  float sum = 0.f;
#pragma unroll
  for (int i = 0; i < 5; i++) {
    int idx = t + i * 256;
    if (idx < 1032) { x[i] = expf(x[i] - mx); sum += x[i]; }
  }
  sum = wred_sum(sum);
  if (l == 0) sh[w] = sum;
  __syncthreads();
  float inv = 1.0f / (sh[0] + sh[1] + sh[2] + sh[3]);
#pragma unroll
  for (int i = 0; i < 5; i++) {
    int idx = t + i * 256;
    if (idx < 1032) p[idx] = (f16)(x[i] * inv);
  }
}

__global__ __launch_bounds__(256) void k_s(const f16* __restrict__ lg,
    const bf16* __restrict__ kvbuf, bf16* __restrict__ s) {
  int b = blockIdx.x >> 4, kt = blockIdx.x & 15;
  int t = threadIdx.x;
  __shared__ f16 wl[8 * 1040];
  for (int h = 0; h < 8; h++)
    for (int i = t; i < 1032; i += 256)
      wl[h * 1040 + i] = lg[(size_t)(b * 8 + h) * 1032 + i];
  __syncthreads();
  int k = kt * 64 + (t & 63), h0 = t >> 6;
  const bf16* kvb = kvbuf + (size_t)b * 1032 * DD + k;
  float a0 = 0.f, a1 = 0.f;
#pragma unroll 4
  for (int p = 0; p < 1032; p++) {
    float kvv = (float)kvb[(size_t)p * DD];
    a0 += (float)wl[h0 * 1040 + p] * kvv;
    a1 += (float)wl[(h0 + 4) * 1040 + p] * kvv;
  }
  s[(size_t)(b * 8 + h0) * DD + k] = (bf16)a0;
  s[(size_t)(b * 8 + h0 + 4) * DD + k] = (bf16)a1;
}

__global__ __launch_bounds__(256) void k_ov(const bf16* __restrict__ s,
    const float* __restrict__ Wi, const float* __restrict__ bi, float* __restrict__ o) {
  int idx = blockIdx.x * 4 + (threadIdx.x >> 6);
  int l = threadIdx.x & 63;
  int b = idx >> 10, n = idx & 1023, h = n >> 7;
  const bf16* sr = s + (size_t)(b * 8 + h) * DD;
  const float* wr = Wi + (size_t)(2048 + n) * DD;
  float acc = 0.f;
#pragma unroll
  for (int k0 = 0; k0 < 1024; k0 += 64) acc += (float)sr[k0 + l] * wr[k0 + l];
  acc = wred_sum(acc);
  if (l == 0) o[idx] = acc + bi[2048 + n];
}

// ---------- tail GEMVs ----------
template <int MODE>
__global__ __launch_bounds__(256) void k_gemv(const float* __restrict__ xin,
    const float* __restrict__ W, const float* __restrict__ bias,
    const float* __restrict__ res, float* __restrict__ outf) {
  int idx = blockIdx.x * 4 + (threadIdx.x >> 6);
  int l = threadIdx.x & 63;
  int b = idx >> 10, n = idx & 1023;
  const float* xr = xin + (size_t)b * DD;
  const float* wr = W + (size_t)n * DD;
  float acc = 0.f;
#pragma unroll
  for (int k0 = 0; k0 < 1024; k0 += 64) acc += xr[k0 + l] * wr[k0 + l];
  acc = wred_sum(acc);
  if (l == 0) {
    float v = acc + bias[n];
    if (MODE == 0) outf[idx] = res[idx] + v;
    if (MODE == 1) outf[idx] = 0.5f * v * (1.0f + erff(v * 0.70710678118654752f));
    if (MODE == 2) outf[idx] = res[idx] + v;
    if (MODE == 3) outf[O_Y + idx] = v;
  }
}

extern "C" void kernel_launch(void* const* d_in, const int* in_sizes, int n_in,
                              void* d_out, int out_size, void* d_ws, size_t ws_size,
                              hipStream_t stream) {
  const float* x        = (const float*)d_in[0];
  const float* state_in = (const float*)d_in[1];
  const float* W_rg     = (const float*)d_in[2];
  const float* ln_moe_g = (const float*)d_in[3];
  const float* ln_moe_b = (const float*)d_in[4];
  const float* W_gate   = (const float*)d_in[5];
  const float* A_skew   = (const float*)d_in[6];
  const float* ln_sl_g  = (const float*)d_in[7];
  const float* ln_sl_b  = (const float*)d_in[8];
  const float* W_slot   = (const float*)d_in[9];
  const float* W_oe     = (const float*)d_in[10];
  const float* b_oe     = (const float*)d_in[11];
  const float* ln_q_g   = (const float*)d_in[12];
  const float* ln_q_b   = (const float*)d_in[13];
  const float* ln_kv_g  = (const float*)d_in[14];
  const float* ln_kv_b  = (const float*)d_in[15];
  const float* in_w     = (const float*)d_in[16];
  const float* in_b     = (const float*)d_in[17];
  const float* out_w    = (const float*)d_in[18];
  const float* out_b    = (const float*)d_in[19];
  const float* ln_f_g   = (const float*)d_in[20];
  const float* ln_f_b   = (const float*)d_in[21];
  const float* W_fc1    = (const float*)d_in[22];
  const float* b_fc1    = (const float*)d_in[23];
  const float* W_fc2    = (const float*)d_in[24];
  const float* b_fc2    = (const float*)d_in[25];
  const float* W_out    = (const float*)d_in[26];
  const float* b_out    = (const float*)d_in[27];

  char* ws = (char*)d_ws;
  bf16*  kvbuf    = (bf16*)(ws + W_KV);
  float* state_ws = (float*)(ws + W_STATE);
  float* u_buf    = (float*)(ws + W_STATE);
  bf16*  s_buf    = (bf16*)(ws + W_STATE);
  float* lat_last = (float*)(ws + W_LATL);
  float* qln      = (float*)(ws + W_QLN);
  float* c0       = (float*)(ws + W_QLN);
  float* r2       = (float*)(ws + W_R2);
  float* rsc      = (float*)(ws + W_RSC);
  float* ssc      = (float*)(ws + W_SSC);
  float* qp       = (float*)(ws + W_OATT);
  f16*   lg       = (f16*)(ws + W_OATT);
  float* o_attn   = (float*)(ws + W_OATT);
  float* lat1     = (float*)(ws + W_LAT1);
  float* lnffn    = (float*)(ws + W_LNFFN);
  float* h1       = (float*)(ws + W_H1);
  float* lat2     = (float*)(ws + W_LAT2);
  float* out = (float*)d_out;

  k_r2<<<1024, 256, 0, stream>>>(A_skew, r2);
  k_scores<<<64, 256, 0, stream>>>(state_in, W_rg, ln_sl_g, ln_sl_b, W_slot, rsc, ssc);
  k_gate<<<32, 256, 0, stream>>>(state_in, rsc, ln_moe_g, ln_moe_b, W_gate, out);
  k_state<<<8, 256, 0, stream>>>(state_in, rsc, ssc, r2, state_ws, out);
  k_gemm<<<dim3(8, 64), 256, 0, stream>>>(x, W_oe, b_oe, kvbuf, lat_last);
  k_ln<<<8256, 256, 0, stream>>>(kvbuf, state_ws, ln_kv_g, ln_kv_b, ln_q_g, ln_q_b, qln, lat_last);
  k_qp<<<2048, 256, 0, stream>>>(qln, in_w, in_b, qp);
  k_c0<<<1, 256, 0, stream>>>(qp, in_b, c0);
  k_u<<<128, 256, 0, stream>>>(qp, in_w, u_buf);
  k_lg<<<264, 256, 0, stream>>>(u_buf, kvbuf, c0, lg);
  k_sm<<<64, 256, 0, stream>>>(lg);
  k_s<<<128, 256, 0, stream>>>(lg, kvbuf, s_buf);
  k_ov<<<2048, 256, 0, stream>>>(s_buf, in_w, in_b, o_attn);
  k_gemv<0><<<2048, 256, 0, stream>>>(o_attn, out_w, out_b, lat_last, lat1);
  k_ln_row<<<8, 256, 0, stream>>>(lat1, ln_f_g, ln_f_b, lnffn);
  k_gemv<1><<<2048, 256, 0, stream>>>(lnffn, W_fc1, b_fc1, nullptr, h1);
  k_gemv<2><<<2048, 256, 0, stream>>>(h1, W_fc2, b_fc2, lat1, lat2);
  k_gemv<3><<<2048, 256, 0, stream>>>(lat2, W_out, b_out, nullptr, out);
}